// Round 8
// baseline (2290.950 us; speedup 1.0000x reference)
//
#include <hip/hip_runtime.h>
#include <cmath>

static constexpr float SCALE_ = 0.17677669529663687f; // 32^-0.5

typedef __attribute__((ext_vector_type(8))) short bf16x8;
typedef __attribute__((ext_vector_type(8))) ushort u16x8;
typedef __attribute__((ext_vector_type(4))) float f32x4;

__device__ inline ushort bf16h(float f) {
    uint x = __float_as_uint(f);
    return (ushort)((x + 0x7fffu + ((x >> 16) & 1u)) >> 16);
}
__device__ inline float bf16f(ushort u) {
    return __uint_as_float(((uint)u) << 16);
}

// async global->LDS, 16B per lane; LDS dest = wave-uniform base + lane*16
__device__ __forceinline__ void gld16(const ushort* g, ushort* l) {
    __builtin_amdgcn_global_load_lds(
        (const __attribute__((address_space(1))) unsigned int*)g,
        (__attribute__((address_space(3))) unsigned int*)l,
        16, 0, 0);
}

// ---------------------------------------------------------------------------
// Small weight-combine GEMM (f32): out[m,n] = scale * sum_k Wa[m,k]*Wb[k,n]
// ---------------------------------------------------------------------------
__global__ __launch_bounds__(256) void smallmm_kernel(
    const float* __restrict__ Wa, const float* __restrict__ Wb,
    const float* __restrict__ scale_p, float* __restrict__ out, int NCb)
{
    int idx = blockIdx.x * 256 + threadIdx.x;
    int n4  = NCb >> 2;
    int m   = idx / n4;
    int n0  = (idx - m * n4) << 2;
    if (m >= 192) return;
    float s = scale_p[0];
    float ax = 0.f, ay = 0.f, az = 0.f, aw = 0.f;
    for (int k = 0; k < 192; ++k) {
        float a = Wa[m * 192 + k];
        const float4 b = *(const float4*)(Wb + (size_t)k * NCb + n0);
        ax += a * b.x; ay += a * b.y; az += a * b.z; aw += a * b.w;
    }
    float4 r = make_float4(ax * s, ay * s, az * s, aw * s);
    *(float4*)(out + (size_t)m * NCb + n0) = r;
}

// ---------------------------------------------------------------------------
// Activation f32 -> K-slabbed bf16 hi/lo [6][Mc][32]
// ---------------------------------------------------------------------------
__global__ __launch_bounds__(256) void conv_x(
    const float* __restrict__ src, long long src_bs,
    ushort* __restrict__ dh, ushort* __restrict__ dl, int Mc)
{
    const long long SS = (long long)Mc * 32;
    const long long total8 = (long long)Mc * 24;
    for (long long t = (long long)blockIdx.x * 256 + threadIdx.x; t < total8;
         t += (long long)gridDim.x * 256) {
        int m  = (int)(t / 24);
        int c8 = (int)(t - (long long)m * 24) * 8;
        int bb = m / 49, r = m - bb * 49;
        const float* sp = src + (long long)bb * src_bs + r * 192 + c8;
        float4 v0 = *(const float4*)sp;
        float4 v1 = *(const float4*)(sp + 4);
        float f[8] = {v0.x, v0.y, v0.z, v0.w, v1.x, v1.y, v1.z, v1.w};
        u16x8 h8, l8;
        #pragma unroll
        for (int e = 0; e < 8; ++e) {
            ushort hh = bf16h(f[e]);
            h8[e] = hh;
            l8[e] = bf16h(f[e] - bf16f(hh));
        }
        long long o = (long long)(c8 >> 5) * SS + (long long)m * 32 + (c8 & 31);
        *(u16x8*)(dh + o) = h8;
        *(u16x8*)(dl + o) = l8;
    }
}

// ---------------------------------------------------------------------------
// Weight f32 [192][NC] -> K-slabbed transposed bf16 hi/lo [6][NC][32]
// ---------------------------------------------------------------------------
__global__ __launch_bounds__(256) void conv_wT(
    const float* __restrict__ W, int NC,
    ushort* __restrict__ dh, ushort* __restrict__ dl)
{
    int idx = blockIdx.x * 256 + threadIdx.x;
    if (idx >= NC * 192) return;
    int n = idx / 192, k = idx - n * 192;
    float f = W[(long long)k * NC + n];
    long long o = ((long long)(k >> 5) * NC + n) * 32 + (k & 31);
    ushort hh = bf16h(f);
    dh[o] = hh;
    dl[o] = bf16h(f - bf16f(hh));
}

// ---------------------------------------------------------------------------
// Double-buffered (T3 minimum 2-phase) split-bf16 MFMA GEMM on slabbed planes.
// A: [6][M][32] hi/lo; W: [6][NC][32] hi/lo. Per 32-K slab, stage A(64x32)
// and B(192x32) via global_load_lds w16 into buf^1 BEFORE computing buf, one
// barrier per slab (its vmcnt(0) drain lands after compute -> latency hidden).
// Source chunk pre-swizzled c ^= (row>>1)&3, same XOR on ds_read (0 conflicts,
// verified r7). Block 64M x 192N, 4 waves (2m x 2n), wave 32x96.
// OUTMODE 0: slabbed hi/lo out; cols >= vcol0 go TRANSPOSED per (head,batch)
//            to vT [6][NB][32][64] hi/lo (attn PV fragment layout, r6-proven).
// OUTMODE 1: f32 scatter (b2=m/49, row stride 192).
// A stage may overread <=4KB past plane tail; launcher pads workspace 64KB.
// ---------------------------------------------------------------------------
template<int NC, bool DUAL, int OUTMODE>
__global__ __launch_bounds__(256, 2) void gemm_db(
    const ushort* __restrict__ Ah1, const ushort* __restrict__ Al1,
    const ushort* __restrict__ Ah2, const ushort* __restrict__ Al2,
    const ushort* __restrict__ Bh1, const ushort* __restrict__ Bl1,
    const ushort* __restrict__ Bh2, const ushort* __restrict__ Bl2,
    const float* __restrict__ bias,
    ushort* __restrict__ outH, ushort* __restrict__ outL,
    int vcol0, ushort* __restrict__ vTh, ushort* __restrict__ vTl, int NB,
    float* __restrict__ outF, long long out_bs,
    int M)
{
    __shared__ __align__(16) ushort AHs[2][2048];   // 64 x 32 per buf
    __shared__ __align__(16) ushort ALs[2][2048];
    __shared__ __align__(16) ushort BHs[2][6144];   // 192 x 32 per buf
    __shared__ __align__(16) ushort BLs[2][6144];

    const int tid = threadIdx.x;
    const int lane = tid & 63, wv = tid >> 6;
    const int wm = (wv >> 1) * 32;
    const int wn = (wv & 1) * 96;
    const int lr = lane & 15, lg = lane >> 4;
    const int bn = blockIdx.x, bm = blockIdx.y;
    const long long SS = (long long)M * 32;
    constexpr int NS = DUAL ? 12 : 6;

    // staging source offsets (swizzled chunk)
    const int at_row = tid >> 2;
    const int at_c   = (tid & 3) ^ ((tid >> 3) & 3);
    const long long a_src = (long long)(bm * 64 + at_row) * 32 + at_c * 8;
    int b_src[3];
    #pragma unroll
    for (int k = 0; k < 3; ++k) {
        int t = k * 256 + tid;
        int row = t >> 2, c = (t & 3) ^ ((t >> 3) & 3);
        b_src[k] = (bn * 192 + row) * 32 + c * 8;
    }
    const int wdst = wv * 512;   // wave-uniform LDS base (ushorts)

    // ds_read fragment offsets (swizzled)
    int aoff[2], boff[6];
    #pragma unroll
    for (int i = 0; i < 2; ++i) {
        int row = wm + 16 * i + lr;
        aoff[i] = (row * 4 + (lg ^ ((row >> 1) & 3))) * 8;
    }
    #pragma unroll
    for (int j = 0; j < 6; ++j) {
        int row = wn + 16 * j + lr;
        boff[j] = (row * 4 + (lg ^ ((row >> 1) & 3))) * 8;
    }

    f32x4 acc[2][6] = {};

    auto stage = [&](int buf, int s) {
        const int k6 = (s < 6) ? s : s - 6;
        const ushort* AHp = (!DUAL || s < 6) ? Ah1 : Ah2;
        const ushort* ALp = (!DUAL || s < 6) ? Al1 : Al2;
        const ushort* BHp = (!DUAL || s < 6) ? Bh1 : Bh2;
        const ushort* BLp = (!DUAL || s < 6) ? Bl1 : Bl2;
        const long long asb = (long long)k6 * SS;
        const int bsb = k6 * (NC * 32);
        gld16(AHp + asb + a_src, &AHs[buf][wdst]);
        gld16(ALp + asb + a_src, &ALs[buf][wdst]);
        #pragma unroll
        for (int k = 0; k < 3; ++k) {
            gld16(BHp + bsb + b_src[k], &BHs[buf][k * 2048 + wdst]);
            gld16(BLp + bsb + b_src[k], &BLs[buf][k * 2048 + wdst]);
        }
    };

    stage(0, 0);
    __syncthreads();   // prologue drain

    #pragma unroll
    for (int s = 0; s < NS; ++s) {
        const int cur = s & 1;
        if (s + 1 < NS) stage(cur ^ 1, s + 1);   // in flight across compute

        bf16x8 ah[2], al[2];
        #pragma unroll
        for (int i = 0; i < 2; ++i) {
            ah[i] = *(const bf16x8*)&AHs[cur][aoff[i]];
            al[i] = *(const bf16x8*)&ALs[cur][aoff[i]];
        }
        #pragma unroll
        for (int j = 0; j < 6; ++j) {
            bf16x8 bh = *(const bf16x8*)&BHs[cur][boff[j]];
            bf16x8 bl = *(const bf16x8*)&BLs[cur][boff[j]];
            #pragma unroll
            for (int i = 0; i < 2; ++i) {
                acc[i][j] = __builtin_amdgcn_mfma_f32_16x16x32_bf16(ah[i], bh, acc[i][j], 0, 0, 0);
                acc[i][j] = __builtin_amdgcn_mfma_f32_16x16x32_bf16(ah[i], bl, acc[i][j], 0, 0, 0);
                acc[i][j] = __builtin_amdgcn_mfma_f32_16x16x32_bf16(al[i], bh, acc[i][j], 0, 0, 0);
            }
        }
        __syncthreads();   // drains stage(s+1) vmcnt + guards buf reuse
    }

    // ---- epilogue ----
    #pragma unroll
    for (int j = 0; j < 6; ++j) {
        const int c = bn * 192 + wn + 16 * j + lr;
        const float bv = bias ? bias[c] : 0.f;
        #pragma unroll
        for (int i = 0; i < 2; ++i)
            #pragma unroll
            for (int r = 0; r < 4; ++r) {
                int m = bm * 64 + wm + 16 * i + 4 * lg + r;
                if (m < M) {
                    float f = acc[i][j][r] + bv;
                    if constexpr (OUTMODE == 1) {
                        int b2 = m / 49, r2 = m - b2 * 49;
                        outF[(long long)b2 * out_bs + r2 * 192 + c] = f;
                    } else {
                        ushort hh = bf16h(f);
                        ushort ll = bf16h(f - bf16f(hh));
                        if (c >= vcol0) {
                            int vc = c - vcol0;
                            int h = vc >> 5, dd = vc & 31;
                            int b2 = m / 49, jj = m - b2 * 49;
                            long long o = (((long long)h * NB + b2) << 11) + dd * 64 + jj;
                            vTh[o] = hh;
                            vTl[o] = ll;
                        } else {
                            long long o = (long long)(c >> 5) * SS + (long long)m * 32 + (c & 31);
                            outH[o] = hh;
                            outL[o] = ll;
                        }
                    }
                }
            }
    }
}

// ---------------------------------------------------------------------------
// MFMA differential attention; q/k slabbed [6][M][32] hi/lo, V as transposed
// per-(head,batch) tiles [32][64] hi/lo (r6-proven). One (batch,head)/block,
// 4 waves, swapped QK^T -> lane-local softmax, wave-private P LDS.
// ---------------------------------------------------------------------------
__global__ __launch_bounds__(256, 4) void attn_bf(
    const ushort* __restrict__ qTh, const ushort* __restrict__ qTl,
    const ushort* __restrict__ kTh, const ushort* __restrict__ kTl,
    const ushort* __restrict__ vTth, const ushort* __restrict__ vTtl,
    const ushort* __restrict__ qRh, const ushort* __restrict__ qRl,
    const ushort* __restrict__ kRh, const ushort* __restrict__ kRl,
    const ushort* __restrict__ vTrh, const ushort* __restrict__ vTrl,
    long long SS, int NB,
    const float* __restrict__ rpb, const float* __restrict__ lam_ptr,
    ushort* __restrict__ otH, ushort* __restrict__ otL,
    ushort* __restrict__ orH, ushort* __restrict__ orL)
{
    __shared__ __align__(16) ushort Pth[64][72];
    __shared__ __align__(16) ushort Ptl[64][72];
    __shared__ float bias_s[169];

    const int tid = threadIdx.x;
    const int bb = blockIdx.x / 6;
    const int h  = blockIdx.x - bb * 6;
    const int lane = tid & 63;
    const int w  = tid >> 6;
    const int li = lane & 15;
    const int lg = lane >> 4;
    const long long rowbase = (long long)bb * 49 * 32;
    const long long hb = (long long)h * SS + rowbase;

    for (int idx = tid; idx < 169; idx += 256) bias_s[idx] = rpb[idx * 6 + h];

    float lraw = lam_ptr[0];
    float lam = 1.f / (1.f + __expf(-lraw));
    lam = fminf(fmaxf(lam, 0.01f), 0.99f);

    const int irow = min(w * 16 + li, 48);

    f32x4 st[2][4];
    #pragma unroll
    for (int s = 0; s < 2; ++s) {
        const ushort* qhb = (s ? qRh : qTh) + hb;
        const ushort* qlb = (s ? qRl : qTl) + hb;
        const ushort* khb = (s ? kRh : kTh) + hb;
        const ushort* klb = (s ? kRl : kTl) + hb;

        bf16x8 qh = *(const bf16x8*)(qhb + irow * 32 + 8 * lg);
        bf16x8 ql = *(const bf16x8*)(qlb + irow * 32 + 8 * lg);
        #pragma unroll
        for (int jt = 0; jt < 4; ++jt) {
            int jr = jt * 16 + li; if (jr > 48) jr = 48;
            bf16x8 kh = *(const bf16x8*)(khb + jr * 32 + 8 * lg);
            bf16x8 kl = *(const bf16x8*)(klb + jr * 32 + 8 * lg);
            f32x4 c = {};
            c = __builtin_amdgcn_mfma_f32_16x16x32_bf16(kh, qh, c, 0, 0, 0);
            c = __builtin_amdgcn_mfma_f32_16x16x32_bf16(kh, ql, c, 0, 0, 0);
            c = __builtin_amdgcn_mfma_f32_16x16x32_bf16(kl, qh, c, 0, 0, 0);
            st[s][jt] = c;
        }
    }
    __syncthreads();   // bias_s ready (only barrier)

    const int ri = (irow * 9363) >> 16;
    const int ci = irow - 7 * ri;
    float bias_v[4][4];
    #pragma unroll
    for (int jt = 0; jt < 4; ++jt)
        #pragma unroll
        for (int r = 0; r < 4; ++r) {
            int j = jt * 16 + 4 * lg + r;
            int jc = (j < 49) ? j : 48;
            int rj = (jc * 9363) >> 16;
            int cj = jc - 7 * rj;
            bias_v[jt][r] = bias_s[(ri - rj + 6) * 13 + (ci - cj + 6)];
        }

    float p[2][4][4];
    #pragma unroll
    for (int s = 0; s < 2; ++s) {
        float m = -1e30f;
        #pragma unroll
        for (int jt = 0; jt < 4; ++jt)
            #pragma unroll
            for (int r = 0; r < 4; ++r) {
                int j = jt * 16 + 4 * lg + r;
                float sv = (j < 49) ? (st[s][jt][r] * SCALE_ + bias_v[jt][r]) : -1e30f;
                p[s][jt][r] = sv;
                m = fmaxf(m, sv);
            }
        m = fmaxf(m, __shfl_xor(m, 16));
        m = fmaxf(m, __shfl_xor(m, 32));
        float sum = 0.f;
        #pragma unroll
        for (int jt = 0; jt < 4; ++jt)
            #pragma unroll
            for (int r = 0; r < 4; ++r) {
                float e = __expf(p[s][jt][r] - m);
                p[s][jt][r] = e;
                sum += e;
            }
        sum += __shfl_xor(sum, 16);
        sum += __shfl_xor(sum, 32);
        float inv = 1.f / sum;
        #pragma unroll
        for (int jt = 0; jt < 4; ++jt)
            #pragma unroll
            for (int r = 0; r < 4; ++r)
                p[s][jt][r] *= inv;
    }

    const int prow = w * 16 + li;
    #pragma unroll
    for (int s = 0; s < 2; ++s) {
        #pragma unroll
        for (int jt = 0; jt < 4; ++jt) {
            ushort4 h4, l4;
            #pragma unroll
            for (int r = 0; r < 4; ++r) {
                float at = p[0][jt][r], ar = p[1][jt][r];
                float f = (s == 0) ? (at - lam * ar) : (ar - lam * at);
                ushort hh = bf16h(f);
                ((ushort*)&h4)[r] = hh;
                ((ushort*)&l4)[r] = bf16h(f - bf16f(hh));
            }
            *(ushort4*)&Pth[prow][jt * 16 + 4 * lg] = h4;
            *(ushort4*)&Ptl[prow][jt * 16 + 4 * lg] = l4;
        }

        const ushort* vth = (s ? vTrh : vTth) + (((long long)h * NB + bb) << 11);
        const ushort* vtl = (s ? vTrl : vTtl) + (((long long)h * NB + bb) << 11);
        f32x4 acc[2] = {};
        #pragma unroll
        for (int ks = 0; ks < 2; ++ks) {
            bf16x8 pah = *(const bf16x8*)&Pth[prow][ks * 32 + 8 * lg];
            bf16x8 pal = *(const bf16x8*)&Ptl[prow][ks * 32 + 8 * lg];
            #pragma unroll
            for (int dt = 0; dt < 2; ++dt) {
                bf16x8 vh = *(const bf16x8*)(vth + (dt * 16 + li) * 64 + ks * 32 + 8 * lg);
                bf16x8 vl = *(const bf16x8*)(vtl + (dt * 16 + li) * 64 + ks * 32 + 8 * lg);
                acc[dt] = __builtin_amdgcn_mfma_f32_16x16x32_bf16(pah, vh, acc[dt], 0, 0, 0);
                acc[dt] = __builtin_amdgcn_mfma_f32_16x16x32_bf16(pah, vl, acc[dt], 0, 0, 0);
                acc[dt] = __builtin_amdgcn_mfma_f32_16x16x32_bf16(pal, vh, acc[dt], 0, 0, 0);
            }
        }
        ushort* oph = s ? orH : otH;
        ushort* opl = s ? orL : otL;
        #pragma unroll
        for (int dt = 0; dt < 2; ++dt)
            #pragma unroll
            for (int r = 0; r < 4; ++r) {
                int i = w * 16 + 4 * lg + r;
                if (i < 49) {
                    long long o = (long long)h * SS + rowbase + (long long)i * 32 + dt * 16 + li;
                    float f = acc[dt][r];
                    ushort hh = bf16h(f);
                    oph[o] = hh;
                    opl[o] = bf16h(f - bf16f(hh));
                }
            }
    }
}

// ---------------------------------------------------------------------------
extern "C" void kernel_launch(void* const* d_in, const int* in_sizes, int n_in,
                              void* d_out, int out_size, void* d_ws, size_t ws_size,
                              hipStream_t stream)
{
    const float* x_sa      = (const float*)d_in[0];
    const float* x_ca      = (const float*)d_in[1];
    const float* lam_sa    = (const float*)d_in[2];
    const float* lam_ca    = (const float*)d_in[3];
    const float* sa_enh    = (const float*)d_in[4];
    const float* ca_enh    = (const float*)d_in[5];
    const float* W_sa_qkv  = (const float*)d_in[6];
    const float* b_sa_qkv  = (const float*)d_in[7];
    const float* W_sa_ct   = (const float*)d_in[8];
    const float* W_sa_cr   = (const float*)d_in[9];
    const float* W_ca_q    = (const float*)d_in[10];
    const float* b_ca_q    = (const float*)d_in[11];
    const float* W_ca_kv   = (const float*)d_in[12];
    const float* b_ca_kv   = (const float*)d_in[13];
    const float* W_ca_ct   = (const float*)d_in[14];
    const float* W_ca_cr   = (const float*)d_in[15];
    const float* rpb       = (const float*)d_in[16];
    const float* W_proj_sa = (const float*)d_in[17];
    const float* b_proj_sa = (const float*)d_in[18];
    const float* W_proj_ca = (const float*)d_in[19];
    const float* b_proj_ca = (const float*)d_in[20];
    float* out = (float*)d_out;
    float* ws  = (float*)d_ws;

    // ---- f32 combined-weight temps ----
    float* CW0 = ws;             // 192x576
    float* CW1 = CW0 + 110592;
    float* CW2 = CW1 + 110592;   // 192x192
    float* CW3 = CW2 + 36864;
    float* CW4 = CW3 + 36864;    // 192x384
    float* CW5 = CW4 + 73728;

    smallmm_kernel<<<108, 256, 0, stream>>>(W_sa_cr, W_sa_qkv, sa_enh, CW0, 576);
    smallmm_kernel<<<108, 256, 0, stream>>>(W_sa_ct, W_sa_qkv, sa_enh, CW1, 576);
    smallmm_kernel<<< 36, 256, 0, stream>>>(W_ca_cr, W_ca_q,   ca_enh, CW2, 192);
    smallmm_kernel<<< 36, 256, 0, stream>>>(W_ca_ct, W_ca_q,   ca_enh, CW3, 192);
    smallmm_kernel<<< 72, 256, 0, stream>>>(W_ca_cr, W_ca_kv,  ca_enh, CW4, 384);
    smallmm_kernel<<< 72, 256, 0, stream>>>(W_ca_ct, W_ca_kv,  ca_enh, CW5, 384);

    // ---- K-slabbed bf16 hi/lo weights ----
    ushort* wb = (ushort*)(ws + 442368);
    ushort* WsaqH = wb;                  ushort* WsaqL = WsaqH + 110592;
    ushort* C0H  = WsaqL + 110592;       ushort* C0L  = C0H + 110592;
    ushort* C1H  = C0L + 110592;         ushort* C1L  = C1H + 110592;
    ushort* WcqH = C1L + 110592;         ushort* WcqL = WcqH + 36864;
    ushort* C2H  = WcqL + 36864;         ushort* C2L  = C2H + 36864;
    ushort* C3H  = C2L + 36864;          ushort* C3L  = C3H + 36864;
    ushort* WckH = C3L + 36864;          ushort* WckL = WckH + 73728;
    ushort* C4H  = WckL + 73728;         ushort* C4L  = C4H + 73728;
    ushort* C5H  = C4L + 73728;          ushort* C5L  = C5H + 73728;
    ushort* WpsH = C5L + 73728;          ushort* WpsL = WpsH + 36864;
    ushort* WpcH = WpsL + 36864;         ushort* WpcL = WpcH + 36864;
    ushort* chunkU = WpcL + 36864;       // = wb + 1474560

    conv_wT<<<432, 256, 0, stream>>>(W_sa_qkv, 576, WsaqH, WsaqL);
    conv_wT<<<432, 256, 0, stream>>>(CW0,      576, C0H,  C0L);
    conv_wT<<<432, 256, 0, stream>>>(CW1,      576, C1H,  C1L);
    conv_wT<<<144, 256, 0, stream>>>(W_ca_q,   192, WcqH, WcqL);
    conv_wT<<<144, 256, 0, stream>>>(CW2,      192, C2H,  C2L);
    conv_wT<<<144, 256, 0, stream>>>(CW3,      192, C3H,  C3L);
    conv_wT<<<288, 256, 0, stream>>>(W_ca_kv,  384, WckH, WckL);
    conv_wT<<<288, 256, 0, stream>>>(CW4,      384, C4H,  C4L);
    conv_wT<<<288, 256, 0, stream>>>(CW5,      384, C5H,  C5L);
    conv_wT<<<144, 256, 0, stream>>>(W_proj_sa,192, WpsH, WpsL);
    conv_wT<<<144, 256, 0, stream>>>(W_proj_ca,192, WpcH, WpcL);

    // ---- chunking: 399360 bytes per batch element, 64KB tail pad ----
    long long avail = (long long)ws_size - 442368LL * 4 - 1474560LL * 2 - 65536;
    int cbmax = (int)(avail / 399360);
    if (cbmax > 2048) cbmax = 2048;
    if (cbmax < 1) cbmax = 1;

    const long long OUT1 = 2LL * 2048 * 49 * 192;
    dim3 blk(256);
    const int BIGC = 1 << 30;

    for (int c0 = 0; c0 < 2048; c0 += cbmax) {
        int cb = (c0 + cbmax <= 2048) ? cbmax : (2048 - c0);
        int M = cb * 49;
        long long SS = (long long)M * 32;
        int gy = (M + 63) / 64;
        int cblk = (int)(((long long)M * 24 + 255) / 256);
        if (cblk > 4096) cblk = 4096;

        dim3 g1(3, gy), g2(1, gy), g3(2, gy);

        // =========================== SA branch ===========================
        ushort* XtH = chunkU;                              // [6][M][32] each
        ushort* XtL = XtH + (long long)cbmax * 9408;
        ushort* XrH = XtL + (long long)cbmax * 9408;
        ushort* XrL = XrH + (long long)cbmax * 9408;
        ushort* QtH = XrL + (long long)cbmax * 9408;       // q,k: [12][M][32]
        ushort* QtL = QtH + (long long)cbmax * 18816;
        ushort* QrH = QtL + (long long)cbmax * 18816;
        ushort* QrL = QrH + (long long)cbmax * 18816;
        ushort* VtTH = QrL + (long long)cbmax * 18816;     // vT: [6][NB][32][64]
        ushort* VtTL = VtTH + (long long)cbmax * 12288;
        ushort* VrTH = VtTL + (long long)cbmax * 12288;
        ushort* VrTL = VrTH + (long long)cbmax * 12288;
        ushort* OtH = VrTL + (long long)cbmax * 12288;     // [6][M][32]
        ushort* OtL = OtH + (long long)cbmax * 9408;
        ushort* OrH = OtL + (long long)cbmax * 9408;
        ushort* OrL = OrH + (long long)cbmax * 9408;

        conv_x<<<cblk, blk, 0, stream>>>(x_sa + (long long)c0 * 9408, 9408, XtH, XtL, M);
        conv_x<<<cblk, blk, 0, stream>>>(x_sa + (2048LL + c0) * 9408, 9408, XrH, XrL, M);

        gemm_db<576, true, 0><<<g1, blk, 0, stream>>>(
            XtH, XtL, XrH, XrL, WsaqH, WsaqL, C0H, C0L,
            b_sa_qkv, QtH, QtL, 384, VtTH, VtTL, cb, nullptr, 0, M);
        gemm_db<576, true, 0><<<g1, blk, 0, stream>>>(
            XrH, XrL, XtH, XtL, WsaqH, WsaqL, C1H, C1L,
            b_sa_qkv, QrH, QrL, 384, VrTH, VrTL, cb, nullptr, 0, M);

        attn_bf<<<cb * 6, blk, 0, stream>>>(
            QtH,          QtL,
            QtH + 6 * SS, QtL + 6 * SS,
            VtTH,         VtTL,
            QrH,          QrL,
            QrH + 6 * SS, QrL + 6 * SS,
            VrTH,         VrTL,
            SS, cb, rpb, lam_sa, OtH, OtL, OrH, OrL);

        gemm_db<192, false, 1><<<g2, blk, 0, stream>>>(
            OtH, OtL, nullptr, nullptr, WpsH, WpsL, nullptr, nullptr,
            b_proj_sa, nullptr, nullptr, BIGC, nullptr, nullptr, cb,
            out + (long long)c0 * 9408, 9408, M);
        gemm_db<192, false, 1><<<g2, blk, 0, stream>>>(
            OrH, OrL, nullptr, nullptr, WpsH, WpsL, nullptr, nullptr,
            b_proj_sa, nullptr, nullptr, BIGC, nullptr, nullptr, cb,
            out + (2048LL + c0) * 9408, 9408, M);

        // =========================== CA branch ===========================
        ushort* CXtH = chunkU;                             // [6][M][32]
        ushort* CXtL = CXtH + (long long)cbmax * 9408;
        ushort* CXrH = CXtL + (long long)cbmax * 9408;
        ushort* CXrL = CXrH + (long long)cbmax * 9408;
        ushort* CQtH = CXrL + (long long)cbmax * 9408;     // [6][M][32]
        ushort* CQtL = CQtH + (long long)cbmax * 9408;
        ushort* CQrH = CQtL + (long long)cbmax * 9408;
        ushort* CQrL = CQrH + (long long)cbmax * 9408;
        ushort* KtH  = CQrL + (long long)cbmax * 9408;     // k: [6][M][32]
        ushort* KtL  = KtH + (long long)cbmax * 9408;
        ushort* KrH  = KtL + (long long)cbmax * 9408;
        ushort* KrL  = KrH + (long long)cbmax * 9408;
        ushort* CVtTH = KrL + (long long)cbmax * 9408;     // vT tiles
        ushort* CVtTL = CVtTH + (long long)cbmax * 12288;
        ushort* CVrTH = CVtTL + (long long)cbmax * 12288;
        ushort* CVrTL = CVrTH + (long long)cbmax * 12288;
        ushort* COtH = CVrTL + (long long)cbmax * 12288;   // [6][M][32]
        ushort* COtL = COtH + (long long)cbmax * 9408;
        ushort* COrH = COtL + (long long)cbmax * 9408;
        ushort* COrL = COrH + (long long)cbmax * 9408;

        conv_x<<<cblk, blk, 0, stream>>>(x_ca + (long long)c0 * 18816, 18816, CXtH, CXtL, M);
        conv_x<<<cblk, blk, 0, stream>>>(x_ca + (long long)c0 * 18816 + 9408, 18816, CXrH, CXrL, M);

        gemm_db<192, true, 0><<<g2, blk, 0, stream>>>(
            CXtH, CXtL, CXrH, CXrL, WcqH, WcqL, C2H, C2L,
            b_ca_q, CQtH, CQtL, BIGC, nullptr, nullptr, cb, nullptr, 0, M);
        gemm_db<192, true, 0><<<g2, blk, 0, stream>>>(
            CXrH, CXrL, CXtH, CXtL, WcqH, WcqL, C3H, C3L,
            b_ca_q, CQrH, CQrL, BIGC, nullptr, nullptr, cb, nullptr, 0, M);

        gemm_db<384, true, 0><<<g3, blk, 0, stream>>>(
            CXtH, CXtL, CXrH, CXrL, WckH, WckL, C4H, C4L,
            b_ca_kv, KtH, KtL, 192, CVtTH, CVtTL, cb, nullptr, 0, M);
        gemm_db<384, true, 0><<<g3, blk, 0, stream>>>(
            CXrH, CXrL, CXtH, CXtL, WckH, WckL, C5H, C5L,
            b_ca_kv, KrH, KrL, 192, CVrTH, CVrTL, cb, nullptr, 0, M);

        attn_bf<<<cb * 6, blk, 0, stream>>>(
            CQtH,  CQtL,
            KtH,   KtL,
            CVtTH, CVtTL,
            CQrH,  CQrL,
            KrH,   KrL,
            CVrTH, CVrTL,
            SS, cb, rpb, lam_ca, COtH, COtL, COrH, COrL);

        gemm_db<192, false, 1><<<g2, blk, 0, stream>>>(
            COtH, COtL, nullptr, nullptr, WpcH, WpcL, nullptr, nullptr,
            b_proj_ca, nullptr, nullptr, BIGC, nullptr, nullptr, cb,
            out + OUT1 + (long long)c0 * 18816, 18816, M);
        gemm_db<192, false, 1><<<g2, blk, 0, stream>>>(
            COrH, COrL, nullptr, nullptr, WpcH, WpcL, nullptr, nullptr,
            b_proj_ca, nullptr, nullptr, BIGC, nullptr, nullptr, cb,
            out + OUT1 + (long long)c0 * 18816 + 9408, 18816, M);
    }
}

// Round 9
// 1658.093 us; speedup vs baseline: 1.3817x; 1.3817x over previous
//
#include <hip/hip_runtime.h>
#include <cmath>

static constexpr float SCALE_ = 0.17677669529663687f; // 32^-0.5

typedef __attribute__((ext_vector_type(8))) short bf16x8;
typedef __attribute__((ext_vector_type(8))) ushort u16x8;
typedef __attribute__((ext_vector_type(4))) float f32x4;

__device__ inline ushort bf16h(float f) {
    uint x = __float_as_uint(f);
    return (ushort)((x + 0x7fffu + ((x >> 16) & 1u)) >> 16);
}
__device__ inline float bf16f(ushort u) {
    return __uint_as_float(((uint)u) << 16);
}

// async global->LDS, 16B per lane; LDS dest = wave-uniform base + lane*16
__device__ __forceinline__ void gld16(const ushort* g, ushort* l) {
    __builtin_amdgcn_global_load_lds(
        (const __attribute__((address_space(1))) unsigned int*)g,
        (__attribute__((address_space(3))) unsigned int*)l,
        16, 0, 0);
}

// ---------------------------------------------------------------------------
// Small weight-combine GEMM (f32): out[m,n] = scale * sum_k Wa[m,k]*Wb[k,n]
// ---------------------------------------------------------------------------
__global__ __launch_bounds__(256) void smallmm_kernel(
    const float* __restrict__ Wa, const float* __restrict__ Wb,
    const float* __restrict__ scale_p, float* __restrict__ out, int NCb)
{
    int idx = blockIdx.x * 256 + threadIdx.x;
    int n4  = NCb >> 2;
    int m   = idx / n4;
    int n0  = (idx - m * n4) << 2;
    if (m >= 192) return;
    float s = scale_p[0];
    float ax = 0.f, ay = 0.f, az = 0.f, aw = 0.f;
    for (int k = 0; k < 192; ++k) {
        float a = Wa[m * 192 + k];
        const float4 b = *(const float4*)(Wb + (size_t)k * NCb + n0);
        ax += a * b.x; ay += a * b.y; az += a * b.z; aw += a * b.w;
    }
    float4 r = make_float4(ax * s, ay * s, az * s, aw * s);
    *(float4*)(out + (size_t)m * NCb + n0) = r;
}

// ---------------------------------------------------------------------------
// Activation f32 -> K-slabbed bf16 hi/lo [6][Mc][32]
// ---------------------------------------------------------------------------
__global__ __launch_bounds__(256) void conv_x(
    const float* __restrict__ src, long long src_bs,
    ushort* __restrict__ dh, ushort* __restrict__ dl, int Mc)
{
    const long long SS = (long long)Mc * 32;
    const long long total8 = (long long)Mc * 24;
    for (long long t = (long long)blockIdx.x * 256 + threadIdx.x; t < total8;
         t += (long long)gridDim.x * 256) {
        int m  = (int)(t / 24);
        int c8 = (int)(t - (long long)m * 24) * 8;
        int bb = m / 49, r = m - bb * 49;
        const float* sp = src + (long long)bb * src_bs + r * 192 + c8;
        float4 v0 = *(const float4*)sp;
        float4 v1 = *(const float4*)(sp + 4);
        float f[8] = {v0.x, v0.y, v0.z, v0.w, v1.x, v1.y, v1.z, v1.w};
        u16x8 h8, l8;
        #pragma unroll
        for (int e = 0; e < 8; ++e) {
            ushort hh = bf16h(f[e]);
            h8[e] = hh;
            l8[e] = bf16h(f[e] - bf16f(hh));
        }
        long long o = (long long)(c8 >> 5) * SS + (long long)m * 32 + (c8 & 31);
        *(u16x8*)(dh + o) = h8;
        *(u16x8*)(dl + o) = l8;
    }
}

// ---------------------------------------------------------------------------
// Weight f32 [192][NC] -> K-slabbed transposed bf16 hi/lo [6][NC][32]
// ---------------------------------------------------------------------------
__global__ __launch_bounds__(256) void conv_wT(
    const float* __restrict__ W, int NC,
    ushort* __restrict__ dh, ushort* __restrict__ dl)
{
    int idx = blockIdx.x * 256 + threadIdx.x;
    if (idx >= NC * 192) return;
    int n = idx / 192, k = idx - n * 192;
    float f = W[(long long)k * NC + n];
    long long o = ((long long)(k >> 5) * NC + n) * 32 + (k & 31);
    ushort hh = bf16h(f);
    dh[o] = hh;
    dl[o] = bf16h(f - bf16f(hh));
}

// ---------------------------------------------------------------------------
// m97-structure split-bf16 MFMA GEMM on K-slabbed planes (r7-verified, 217us).
// ---------------------------------------------------------------------------
template<int NC, bool DUAL, bool F32OUT>
__global__ __launch_bounds__(256, 3) void gemm_m97(
    const ushort* __restrict__ Ah1, const ushort* __restrict__ Al1,
    const ushort* __restrict__ Ah2, const ushort* __restrict__ Al2,
    const ushort* __restrict__ Bh1, const ushort* __restrict__ Bl1,
    const ushort* __restrict__ Bh2, const ushort* __restrict__ Bl2,
    const float* __restrict__ bias,
    ushort* __restrict__ outH, ushort* __restrict__ outL,
    float* __restrict__ outF, long long out_bs,
    int M)
{
    __shared__ __align__(16) ushort AHs[2048];   // 64 x 32
    __shared__ __align__(16) ushort ALs[2048];
    __shared__ __align__(16) ushort BHs[6144];   // 192 x 32
    __shared__ __align__(16) ushort BLs[6144];

    const int tid = threadIdx.x;
    const int lane = tid & 63, wv = tid >> 6;
    const int wm = (wv >> 1) * 32;
    const int wn = (wv & 1) * 96;
    const int lr = lane & 15, lg = lane >> 4;
    const int bn = blockIdx.x, bm = blockIdx.y;
    const long long SS = (long long)M * 32;
    constexpr int NS = DUAL ? 12 : 6;

    const int at_row = tid >> 2;
    const int at_c   = (tid & 3) ^ ((tid >> 3) & 3);
    const long long a_src = (long long)(bm * 64 + at_row) * 32 + at_c * 8;
    int b_src[3];
    #pragma unroll
    for (int k = 0; k < 3; ++k) {
        int t = k * 256 + tid;
        int row = t >> 2, c = (t & 3) ^ ((t >> 3) & 3);
        b_src[k] = (bn * 192 + row) * 32 + c * 8;
    }
    const int wdst = wv * 512;

    int aoff[2], boff[6];
    #pragma unroll
    for (int i = 0; i < 2; ++i) {
        int row = wm + 16 * i + lr;
        aoff[i] = (row * 4 + (lg ^ ((row >> 1) & 3))) * 8;
    }
    #pragma unroll
    for (int j = 0; j < 6; ++j) {
        int row = wn + 16 * j + lr;
        boff[j] = (row * 4 + (lg ^ ((row >> 1) & 3))) * 8;
    }

    f32x4 acc[2][6] = {};

    #pragma unroll
    for (int s = 0; s < NS; ++s) {
        const int k6 = (s < 6) ? s : s - 6;
        const ushort* AHp = (!DUAL || s < 6) ? Ah1 : Ah2;
        const ushort* ALp = (!DUAL || s < 6) ? Al1 : Al2;
        const ushort* BHp = (!DUAL || s < 6) ? Bh1 : Bh2;
        const ushort* BLp = (!DUAL || s < 6) ? Bl1 : Bl2;
        const long long asb = (long long)k6 * SS;
        const int bsb = k6 * (NC * 32);

        gld16(AHp + asb + a_src, AHs + wdst);
        gld16(ALp + asb + a_src, ALs + wdst);
        #pragma unroll
        for (int k = 0; k < 3; ++k) {
            gld16(BHp + bsb + b_src[k], BHs + k * 2048 + wdst);
            gld16(BLp + bsb + b_src[k], BLs + k * 2048 + wdst);
        }
        __syncthreads();   // drain vmcnt -> tile visible

        bf16x8 ah[2], al[2];
        #pragma unroll
        for (int i = 0; i < 2; ++i) {
            ah[i] = *(const bf16x8*)&AHs[aoff[i]];
            al[i] = *(const bf16x8*)&ALs[aoff[i]];
        }
        #pragma unroll
        for (int j = 0; j < 6; ++j) {
            bf16x8 bh = *(const bf16x8*)&BHs[boff[j]];
            bf16x8 bl = *(const bf16x8*)&BLs[boff[j]];
            #pragma unroll
            for (int i = 0; i < 2; ++i) {
                acc[i][j] = __builtin_amdgcn_mfma_f32_16x16x32_bf16(ah[i], bh, acc[i][j], 0, 0, 0);
                acc[i][j] = __builtin_amdgcn_mfma_f32_16x16x32_bf16(ah[i], bl, acc[i][j], 0, 0, 0);
                acc[i][j] = __builtin_amdgcn_mfma_f32_16x16x32_bf16(al[i], bh, acc[i][j], 0, 0, 0);
            }
        }
        __syncthreads();   // all reads done before next stage overwrites
    }

    #pragma unroll
    for (int j = 0; j < 6; ++j) {
        const int c = bn * 192 + wn + 16 * j + lr;
        const float bv = bias ? bias[c] : 0.f;
        #pragma unroll
        for (int i = 0; i < 2; ++i)
            #pragma unroll
            for (int r = 0; r < 4; ++r) {
                int m = bm * 64 + wm + 16 * i + 4 * lg + r;
                if (m < M) {
                    float f = acc[i][j][r] + bv;
                    if constexpr (F32OUT) {
                        int b2 = m / 49, r2 = m - b2 * 49;
                        outF[(long long)b2 * out_bs + r2 * 192 + c] = f;
                    } else {
                        long long o = (long long)(c >> 5) * SS + (long long)m * 32 + (c & 31);
                        ushort hh = bf16h(f);
                        outH[o] = hh;
                        outL[o] = bf16h(f - bf16f(hh));
                    }
                }
            }
    }
}

// ---------------------------------------------------------------------------
// MFMA differential attention on K-slabbed hi/lo planes.
// NEW vs r7: V cooperatively staged to LDS TRANSPOSED ([d][j], pad 70) with
// vector global loads; PV B-fragments become ds_read_b128 (was 128 scalar
// global u16 gathers per lane). Pad rows j in [49,64) zeroed in LDS.
// ---------------------------------------------------------------------------
__global__ __launch_bounds__(256, 4) void attn_bf(
    const ushort* __restrict__ qTh, const ushort* __restrict__ qTl,
    const ushort* __restrict__ kTh, const ushort* __restrict__ kTl,
    const ushort* __restrict__ vTh, const ushort* __restrict__ vTl,
    const ushort* __restrict__ qRh, const ushort* __restrict__ qRl,
    const ushort* __restrict__ kRh, const ushort* __restrict__ kRl,
    const ushort* __restrict__ vRh, const ushort* __restrict__ vRl,
    long long SS,
    const float* __restrict__ rpb, const float* __restrict__ lam_ptr,
    ushort* __restrict__ otH, ushort* __restrict__ otL,
    ushort* __restrict__ orH, ushort* __restrict__ orL)
{
    __shared__ __align__(16) ushort Pth[64][72];
    __shared__ __align__(16) ushort Ptl[64][72];
    __shared__ __align__(16) ushort Vs[2][2][32][70];  // [stream][hi/lo][d][j]
    __shared__ float bias_s[169];

    const int tid = threadIdx.x;
    const int bb = blockIdx.x / 6;
    const int h  = blockIdx.x - bb * 6;
    const int lane = tid & 63;
    const int w  = tid >> 6;
    const int li = lane & 15;
    const int lg = lane >> 4;
    const long long rowbase = (long long)bb * 49 * 32;
    const long long hb = (long long)h * SS + rowbase;

    for (int idx = tid; idx < 169; idx += 256) bias_s[idx] = rpb[idx * 6 + h];

    // ---- stage V transposed into LDS: 2s x 2(h/l) x 49j x 4 d-chunks ----
    {
        const ushort* vsrc[2][2] = {{vTh + hb, vTl + hb}, {vRh + hb, vRl + hb}};
        for (int c = tid; c < 784; c += 256) {
            int s  = c / 392;
            int r1 = c - s * 392;
            int hl = r1 / 196;
            int r2 = r1 - hl * 196;
            int j  = r2 >> 2;
            int d4 = (r2 & 3) * 8;
            u16x8 v = *(const u16x8*)(vsrc[s][hl] + j * 32 + d4);
            #pragma unroll
            for (int e = 0; e < 8; ++e) Vs[s][hl][d4 + e][j] = v[e];
        }
        // zero pad rows j in [49,70)
        for (int c = tid; c < 2 * 2 * 32 * 21; c += 256) {
            int s  = c / (2 * 32 * 21);
            int r1 = c - s * (2 * 32 * 21);
            int hl = r1 / (32 * 21);
            int r2 = r1 - hl * (32 * 21);
            int d  = r2 / 21;
            int j  = 49 + (r2 - d * 21);
            Vs[s][hl][d][j] = 0;
        }
    }

    float lraw = lam_ptr[0];
    float lam = 1.f / (1.f + __expf(-lraw));
    lam = fminf(fmaxf(lam, 0.01f), 0.99f);

    const int irow = min(w * 16 + li, 48);

    f32x4 st[2][4];
    #pragma unroll
    for (int s = 0; s < 2; ++s) {
        const ushort* qhb = (s ? qRh : qTh) + hb;
        const ushort* qlb = (s ? qRl : qTl) + hb;
        const ushort* khb = (s ? kRh : kTh) + hb;
        const ushort* klb = (s ? kRl : kTl) + hb;

        bf16x8 qh = *(const bf16x8*)(qhb + irow * 32 + 8 * lg);
        bf16x8 ql = *(const bf16x8*)(qlb + irow * 32 + 8 * lg);
        #pragma unroll
        for (int jt = 0; jt < 4; ++jt) {
            int jr = jt * 16 + li; if (jr > 48) jr = 48;
            bf16x8 kh = *(const bf16x8*)(khb + jr * 32 + 8 * lg);
            bf16x8 kl = *(const bf16x8*)(klb + jr * 32 + 8 * lg);
            f32x4 c = {};
            c = __builtin_amdgcn_mfma_f32_16x16x32_bf16(kh, qh, c, 0, 0, 0);
            c = __builtin_amdgcn_mfma_f32_16x16x32_bf16(kh, ql, c, 0, 0, 0);
            c = __builtin_amdgcn_mfma_f32_16x16x32_bf16(kl, qh, c, 0, 0, 0);
            st[s][jt] = c;
        }
    }
    __syncthreads();   // bias_s + Vs staged (only barrier)

    const int ri = (irow * 9363) >> 16;
    const int ci = irow - 7 * ri;
    float bias_v[4][4];
    #pragma unroll
    for (int jt = 0; jt < 4; ++jt)
        #pragma unroll
        for (int r = 0; r < 4; ++r) {
            int j = jt * 16 + 4 * lg + r;
            int jc = (j < 49) ? j : 48;
            int rj = (jc * 9363) >> 16;
            int cj = jc - 7 * rj;
            bias_v[jt][r] = bias_s[(ri - rj + 6) * 13 + (ci - cj + 6)];
        }

    float p[2][4][4];
    #pragma unroll
    for (int s = 0; s < 2; ++s) {
        float m = -1e30f;
        #pragma unroll
        for (int jt = 0; jt < 4; ++jt)
            #pragma unroll
            for (int r = 0; r < 4; ++r) {
                int j = jt * 16 + 4 * lg + r;
                float sv = (j < 49) ? (st[s][jt][r] * SCALE_ + bias_v[jt][r]) : -1e30f;
                p[s][jt][r] = sv;
                m = fmaxf(m, sv);
            }
        m = fmaxf(m, __shfl_xor(m, 16));
        m = fmaxf(m, __shfl_xor(m, 32));
        float sum = 0.f;
        #pragma unroll
        for (int jt = 0; jt < 4; ++jt)
            #pragma unroll
            for (int r = 0; r < 4; ++r) {
                float e = __expf(p[s][jt][r] - m);
                p[s][jt][r] = e;
                sum += e;
            }
        sum += __shfl_xor(sum, 16);
        sum += __shfl_xor(sum, 32);
        float inv = 1.f / sum;
        #pragma unroll
        for (int jt = 0; jt < 4; ++jt)
            #pragma unroll
            for (int r = 0; r < 4; ++r)
                p[s][jt][r] *= inv;
    }

    const int prow = w * 16 + li;
    #pragma unroll
    for (int s = 0; s < 2; ++s) {
        #pragma unroll
        for (int jt = 0; jt < 4; ++jt) {
            ushort4 h4, l4;
            #pragma unroll
            for (int r = 0; r < 4; ++r) {
                float at = p[0][jt][r], ar = p[1][jt][r];
                float f = (s == 0) ? (at - lam * ar) : (ar - lam * at);
                ushort hh = bf16h(f);
                ((ushort*)&h4)[r] = hh;
                ((ushort*)&l4)[r] = bf16h(f - bf16f(hh));
            }
            *(ushort4*)&Pth[prow][jt * 16 + 4 * lg] = h4;
            *(ushort4*)&Ptl[prow][jt * 16 + 4 * lg] = l4;
        }

        f32x4 acc[2] = {};
        #pragma unroll
        for (int ks = 0; ks < 2; ++ks) {
            bf16x8 pah = *(const bf16x8*)&Pth[prow][ks * 32 + 8 * lg];
            bf16x8 pal = *(const bf16x8*)&Ptl[prow][ks * 32 + 8 * lg];
            #pragma unroll
            for (int dt = 0; dt < 2; ++dt) {
                bf16x8 vh = *(const bf16x8*)&Vs[s][0][dt * 16 + li][ks * 32 + 8 * lg];
                bf16x8 vl = *(const bf16x8*)&Vs[s][1][dt * 16 + li][ks * 32 + 8 * lg];
                acc[dt] = __builtin_amdgcn_mfma_f32_16x16x32_bf16(pah, vh, acc[dt], 0, 0, 0);
                acc[dt] = __builtin_amdgcn_mfma_f32_16x16x32_bf16(pah, vl, acc[dt], 0, 0, 0);
                acc[dt] = __builtin_amdgcn_mfma_f32_16x16x32_bf16(pal, vh, acc[dt], 0, 0, 0);
            }
        }
        ushort* oph = s ? orH : otH;
        ushort* opl = s ? orL : otL;
        #pragma unroll
        for (int dt = 0; dt < 2; ++dt)
            #pragma unroll
            for (int r = 0; r < 4; ++r) {
                int i = w * 16 + 4 * lg + r;
                if (i < 49) {
                    long long o = (long long)h * SS + rowbase + (long long)i * 32 + dt * 16 + li;
                    float f = acc[dt][r];
                    ushort hh = bf16h(f);
                    oph[o] = hh;
                    opl[o] = bf16h(f - bf16f(hh));
                }
            }
    }
}

// ---------------------------------------------------------------------------
extern "C" void kernel_launch(void* const* d_in, const int* in_sizes, int n_in,
                              void* d_out, int out_size, void* d_ws, size_t ws_size,
                              hipStream_t stream)
{
    const float* x_sa      = (const float*)d_in[0];
    const float* x_ca      = (const float*)d_in[1];
    const float* lam_sa    = (const float*)d_in[2];
    const float* lam_ca    = (const float*)d_in[3];
    const float* sa_enh    = (const float*)d_in[4];
    const float* ca_enh    = (const float*)d_in[5];
    const float* W_sa_qkv  = (const float*)d_in[6];
    const float* b_sa_qkv  = (const float*)d_in[7];
    const float* W_sa_ct   = (const float*)d_in[8];
    const float* W_sa_cr   = (const float*)d_in[9];
    const float* W_ca_q    = (const float*)d_in[10];
    const float* b_ca_q    = (const float*)d_in[11];
    const float* W_ca_kv   = (const float*)d_in[12];
    const float* b_ca_kv   = (const float*)d_in[13];
    const float* W_ca_ct   = (const float*)d_in[14];
    const float* W_ca_cr   = (const float*)d_in[15];
    const float* rpb       = (const float*)d_in[16];
    const float* W_proj_sa = (const float*)d_in[17];
    const float* b_proj_sa = (const float*)d_in[18];
    const float* W_proj_ca = (const float*)d_in[19];
    const float* b_proj_ca = (const float*)d_in[20];
    float* out = (float*)d_out;
    float* ws  = (float*)d_ws;

    // ---- f32 combined-weight temps ----
    float* CW0 = ws;             // 192x576
    float* CW1 = CW0 + 110592;
    float* CW2 = CW1 + 110592;   // 192x192
    float* CW3 = CW2 + 36864;
    float* CW4 = CW3 + 36864;    // 192x384
    float* CW5 = CW4 + 73728;

    smallmm_kernel<<<108, 256, 0, stream>>>(W_sa_cr, W_sa_qkv, sa_enh, CW0, 576);
    smallmm_kernel<<<108, 256, 0, stream>>>(W_sa_ct, W_sa_qkv, sa_enh, CW1, 576);
    smallmm_kernel<<< 36, 256, 0, stream>>>(W_ca_cr, W_ca_q,   ca_enh, CW2, 192);
    smallmm_kernel<<< 36, 256, 0, stream>>>(W_ca_ct, W_ca_q,   ca_enh, CW3, 192);
    smallmm_kernel<<< 72, 256, 0, stream>>>(W_ca_cr, W_ca_kv,  ca_enh, CW4, 384);
    smallmm_kernel<<< 72, 256, 0, stream>>>(W_ca_ct, W_ca_kv,  ca_enh, CW5, 384);

    // ---- K-slabbed bf16 hi/lo weights ----
    ushort* wb = (ushort*)(ws + 442368);
    ushort* WsaqH = wb;                  ushort* WsaqL = WsaqH + 110592;
    ushort* C0H  = WsaqL + 110592;       ushort* C0L  = C0H + 110592;
    ushort* C1H  = C0L + 110592;         ushort* C1L  = C1H + 110592;
    ushort* WcqH = C1L + 110592;         ushort* WcqL = WcqH + 36864;
    ushort* C2H  = WcqL + 36864;         ushort* C2L  = C2H + 36864;
    ushort* C3H  = C2L + 36864;          ushort* C3L  = C3H + 36864;
    ushort* WckH = C3L + 36864;          ushort* WckL = WckH + 73728;
    ushort* C4H  = WckL + 73728;         ushort* C4L  = C4H + 73728;
    ushort* C5H  = C4L + 73728;          ushort* C5L  = C5H + 73728;
    ushort* WpsH = C5L + 73728;          ushort* WpsL = WpsH + 36864;
    ushort* WpcH = WpsL + 36864;         ushort* WpcL = WpcH + 36864;
    ushort* chunkU = WpcL + 36864;       // = wb + 1474560

    conv_wT<<<432, 256, 0, stream>>>(W_sa_qkv, 576, WsaqH, WsaqL);
    conv_wT<<<432, 256, 0, stream>>>(CW0,      576, C0H,  C0L);
    conv_wT<<<432, 256, 0, stream>>>(CW1,      576, C1H,  C1L);
    conv_wT<<<144, 256, 0, stream>>>(W_ca_q,   192, WcqH, WcqL);
    conv_wT<<<144, 256, 0, stream>>>(CW2,      192, C2H,  C2L);
    conv_wT<<<144, 256, 0, stream>>>(CW3,      192, C3H,  C3L);
    conv_wT<<<288, 256, 0, stream>>>(W_ca_kv,  384, WckH, WckL);
    conv_wT<<<288, 256, 0, stream>>>(CW4,      384, C4H,  C4L);
    conv_wT<<<288, 256, 0, stream>>>(CW5,      384, C5H,  C5L);
    conv_wT<<<144, 256, 0, stream>>>(W_proj_sa,192, WpsH, WpsL);
    conv_wT<<<144, 256, 0, stream>>>(W_proj_ca,192, WpcH, WpcL);

    // ---- chunking: 376320 bytes per batch element, 64KB tail pad ----
    long long avail = (long long)ws_size - 442368LL * 4 - 1474560LL * 2 - 65536;
    int cbmax = (int)(avail / 376320);
    if (cbmax > 2048) cbmax = 2048;
    if (cbmax < 1) cbmax = 1;

    const long long OUT1 = 2LL * 2048 * 49 * 192;
    dim3 blk(256);

    for (int c0 = 0; c0 < 2048; c0 += cbmax) {
        int cb = (c0 + cbmax <= 2048) ? cbmax : (2048 - c0);
        int M = cb * 49;
        long long SS = (long long)M * 32;
        int gy = (M + 63) / 64;
        int cblk = (int)(((long long)M * 24 + 255) / 256);
        if (cblk > 4096) cblk = 4096;

        dim3 g1(3, gy), g2(1, gy), g3(2, gy);

        // =========================== SA branch ===========================
        ushort* XtH = chunkU;                              // [6][M][32] each
        ushort* XtL = XtH + (long long)cbmax * 9408;
        ushort* XrH = XtL + (long long)cbmax * 9408;
        ushort* XrL = XrH + (long long)cbmax * 9408;
        ushort* QtH = XrL + (long long)cbmax * 9408;       // [18][M][32]
        ushort* QtL = QtH + (long long)cbmax * 28224;
        ushort* QrH = QtL + (long long)cbmax * 28224;
        ushort* QrL = QrH + (long long)cbmax * 28224;
        ushort* OtH = QrL + (long long)cbmax * 28224;      // [6][M][32]
        ushort* OtL = OtH + (long long)cbmax * 9408;
        ushort* OrH = OtL + (long long)cbmax * 9408;
        ushort* OrL = OrH + (long long)cbmax * 9408;

        conv_x<<<cblk, blk, 0, stream>>>(x_sa + (long long)c0 * 9408, 9408, XtH, XtL, M);
        conv_x<<<cblk, blk, 0, stream>>>(x_sa + (2048LL + c0) * 9408, 9408, XrH, XrL, M);

        gemm_m97<576, true, false><<<g1, blk, 0, stream>>>(
            XtH, XtL, XrH, XrL, WsaqH, WsaqL, C0H, C0L,
            b_sa_qkv, QtH, QtL, nullptr, 0, M);
        gemm_m97<576, true, false><<<g1, blk, 0, stream>>>(
            XrH, XrL, XtH, XtL, WsaqH, WsaqL, C1H, C1L,
            b_sa_qkv, QrH, QrL, nullptr, 0, M);

        attn_bf<<<cb * 6, blk, 0, stream>>>(
            QtH,           QtL,
            QtH + 6 * SS,  QtL + 6 * SS,
            QtH + 12 * SS, QtL + 12 * SS,
            QrH,           QrL,
            QrH + 6 * SS,  QrL + 6 * SS,
            QrH + 12 * SS, QrL + 12 * SS,
            SS, rpb, lam_sa, OtH, OtL, OrH, OrL);

        gemm_m97<192, false, true><<<g2, blk, 0, stream>>>(
            OtH, OtL, nullptr, nullptr, WpsH, WpsL, nullptr, nullptr,
            b_proj_sa, nullptr, nullptr, out + (long long)c0 * 9408, 9408, M);
        gemm_m97<192, false, true><<<g2, blk, 0, stream>>>(
            OrH, OrL, nullptr, nullptr, WpsH, WpsL, nullptr, nullptr,
            b_proj_sa, nullptr, nullptr, out + (2048LL + c0) * 9408, 9408, M);

        // =========================== CA branch ===========================
        ushort* CXtH = chunkU;                             // [6][M][32]
        ushort* CXtL = CXtH + (long long)cbmax * 9408;
        ushort* CXrH = CXtL + (long long)cbmax * 9408;
        ushort* CXrL = CXrH + (long long)cbmax * 9408;
        ushort* CQtH = CXrL + (long long)cbmax * 9408;     // [6][M][32]
        ushort* CQtL = CQtH + (long long)cbmax * 9408;
        ushort* CQrH = CQtL + (long long)cbmax * 9408;
        ushort* CQrL = CQrH + (long long)cbmax * 9408;
        ushort* KtH  = CQrL + (long long)cbmax * 9408;     // [12][M][32]
        ushort* KtL  = KtH + (long long)cbmax * 18816;
        ushort* KrH  = KtL + (long long)cbmax * 18816;
        ushort* KrL  = KrH + (long long)cbmax * 18816;
        ushort* COtH = KrL + (long long)cbmax * 18816;     // [6][M][32]
        ushort* COtL = COtH + (long long)cbmax * 9408;
        ushort* COrH = COtL + (long long)cbmax * 9408;
        ushort* COrL = COrH + (long long)cbmax * 9408;

        conv_x<<<cblk, blk, 0, stream>>>(x_ca + (long long)c0 * 18816, 18816, CXtH, CXtL, M);
        conv_x<<<cblk, blk, 0, stream>>>(x_ca + (long long)c0 * 18816 + 9408, 18816, CXrH, CXrL, M);

        gemm_m97<192, true, false><<<g2, blk, 0, stream>>>(
            CXtH, CXtL, CXrH, CXrL, WcqH, WcqL, C2H, C2L,
            b_ca_q, CQtH, CQtL, nullptr, 0, M);
        gemm_m97<192, true, false><<<g2, blk, 0, stream>>>(
            CXrH, CXrL, CXtH, CXtL, WcqH, WcqL, C3H, C3L,
            b_ca_q, CQrH, CQrL, nullptr, 0, M);

        gemm_m97<384, true, false><<<g3, blk, 0, stream>>>(
            CXtH, CXtL, CXrH, CXrL, WckH, WckL, C4H, C4L,
            b_ca_kv, KtH, KtL, nullptr, 0, M);
        gemm_m97<384, true, false><<<g3, blk, 0, stream>>>(
            CXrH, CXrL, CXtH, CXtL, WckH, WckL, C5H, C5L,
            b_ca_kv, KrH, KrL, nullptr, 0, M);

        attn_bf<<<cb * 6, blk, 0, stream>>>(
            CQtH,         CQtL,
            KtH,          KtL,
            KtH + 6 * SS, KtL + 6 * SS,
            CQrH,         CQrL,
            KrH,          KrL,
            KrH + 6 * SS, KrL + 6 * SS,
            SS, rpb, lam_ca, COtH, COtL, COrH, COrL);

        gemm_m97<192, false, true><<<g2, blk, 0, stream>>>(
            COtH, COtL, nullptr, nullptr, WpcH, WpcL, nullptr, nullptr,
            b_proj_ca, nullptr, nullptr,
            out + OUT1 + (long long)c0 * 18816, 18816, M);
        gemm_m97<192, false, true><<<g2, blk, 0, stream>>>(
            COrH, COrL, nullptr, nullptr, WpcH, WpcL, nullptr, nullptr,
            b_proj_ca, nullptr, nullptr,
            out + OUT1 + (long long)c0 * 18816 + 9408, 18816, M);
    }
}

// Round 10
// 898.151 us; speedup vs baseline: 2.5507x; 1.8461x over previous
//
#include <hip/hip_runtime.h>
#include <cmath>

static constexpr float SCALE_ = 0.17677669529663687f; // 32^-0.5

typedef __attribute__((ext_vector_type(8))) _Float16 f16x8;
typedef __attribute__((ext_vector_type(8))) ushort u16x8;
typedef __attribute__((ext_vector_type(4))) float f32x4;

__device__ inline ushort f16u(float f) {
    union { _Float16 h; ushort u; } c;
    c.h = (_Float16)f;
    return c.u;
}

// async global->LDS, 16B per lane; LDS dest = wave-uniform base + lane*16
__device__ __forceinline__ void gld16(const ushort* g, ushort* l) {
    __builtin_amdgcn_global_load_lds(
        (const __attribute__((address_space(1))) unsigned int*)g,
        (__attribute__((address_space(3))) unsigned int*)l,
        16, 0, 0);
}

// ---------------------------------------------------------------------------
// Small weight-combine GEMM (f32): out[m,n] = scale * sum_k Wa[m,k]*Wb[k,n]
// ---------------------------------------------------------------------------
__global__ __launch_bounds__(256) void smallmm_kernel(
    const float* __restrict__ Wa, const float* __restrict__ Wb,
    const float* __restrict__ scale_p, float* __restrict__ out, int NCb)
{
    int idx = blockIdx.x * 256 + threadIdx.x;
    int n4  = NCb >> 2;
    int m   = idx / n4;
    int n0  = (idx - m * n4) << 2;
    if (m >= 192) return;
    float s = scale_p[0];
    float ax = 0.f, ay = 0.f, az = 0.f, aw = 0.f;
    for (int k = 0; k < 192; ++k) {
        float a = Wa[m * 192 + k];
        const float4 b = *(const float4*)(Wb + (size_t)k * NCb + n0);
        ax += a * b.x; ay += a * b.y; az += a * b.z; aw += a * b.w;
    }
    float4 r = make_float4(ax * s, ay * s, az * s, aw * s);
    *(float4*)(out + (size_t)m * NCb + n0) = r;
}

// ---------------------------------------------------------------------------
// Activation f32 -> K-slabbed fp16 [6][Mc][32]
// ---------------------------------------------------------------------------
__global__ __launch_bounds__(256) void conv_x(
    const float* __restrict__ src, long long src_bs,
    ushort* __restrict__ dh, int Mc)
{
    const long long SS = (long long)Mc * 32;
    const long long total8 = (long long)Mc * 24;
    for (long long t = (long long)blockIdx.x * 256 + threadIdx.x; t < total8;
         t += (long long)gridDim.x * 256) {
        int m  = (int)(t / 24);
        int c8 = (int)(t - (long long)m * 24) * 8;
        int bb = m / 49, r = m - bb * 49;
        const float* sp = src + (long long)bb * src_bs + r * 192 + c8;
        float4 v0 = *(const float4*)sp;
        float4 v1 = *(const float4*)(sp + 4);
        float f[8] = {v0.x, v0.y, v0.z, v0.w, v1.x, v1.y, v1.z, v1.w};
        u16x8 h8;
        #pragma unroll
        for (int e = 0; e < 8; ++e) h8[e] = f16u(f[e]);
        long long o = (long long)(c8 >> 5) * SS + (long long)m * 32 + (c8 & 31);
        *(u16x8*)(dh + o) = h8;
    }
}

// ---------------------------------------------------------------------------
// Weight f32 [192][NC] -> K-slabbed transposed fp16 [6][NC][32]
// ---------------------------------------------------------------------------
__global__ __launch_bounds__(256) void conv_wT(
    const float* __restrict__ W, int NC, ushort* __restrict__ dh)
{
    int idx = blockIdx.x * 256 + threadIdx.x;
    if (idx >= NC * 192) return;
    int n = idx / 192, k = idx - n * 192;
    float f = W[(long long)k * NC + n];
    long long o = ((long long)(k >> 5) * NC + n) * 32 + (k & 31);
    dh[o] = f16u(f);
}

// ---------------------------------------------------------------------------
// m97-structure fp16 MFMA GEMM on K-slabbed planes (structure r7-verified).
// A: [6][M][32] fp16; W: [6][NC][32] fp16. Per 32-K slab: A(64x32)+B(192x32)
// staged via global_load_lds w16 (linear dest, src chunk c ^= (row>>1)&3,
// same XOR on ds_read -> 0 conflicts). Block 64M x 192N, 4 waves, wave 32x96.
// F32OUT: f32 scatter (b2=m/49, row stride 192); else slabbed fp16 out.
// A stage may overread <=2KB past plane tail; launcher pads workspace 64KB.
// ---------------------------------------------------------------------------
template<int NC, bool DUAL, bool F32OUT>
__global__ __launch_bounds__(256, 4) void gemm_f16(
    const ushort* __restrict__ Ah1, const ushort* __restrict__ Ah2,
    const ushort* __restrict__ Bh1, const ushort* __restrict__ Bh2,
    const float* __restrict__ bias,
    ushort* __restrict__ outH,
    float* __restrict__ outF, long long out_bs,
    int M)
{
    __shared__ __align__(16) ushort AHs[2048];   // 64 x 32
    __shared__ __align__(16) ushort BHs[6144];   // 192 x 32

    const int tid = threadIdx.x;
    const int lane = tid & 63, wv = tid >> 6;
    const int wm = (wv >> 1) * 32;
    const int wn = (wv & 1) * 96;
    const int lr = lane & 15, lg = lane >> 4;
    const int bn = blockIdx.x, bm = blockIdx.y;
    const long long SS = (long long)M * 32;
    constexpr int NS = DUAL ? 12 : 6;

    const int at_row = tid >> 2;
    const int at_c   = (tid & 3) ^ ((tid >> 3) & 3);
    const long long a_src = (long long)(bm * 64 + at_row) * 32 + at_c * 8;
    int b_src[3];
    #pragma unroll
    for (int k = 0; k < 3; ++k) {
        int t = k * 256 + tid;
        int row = t >> 2, c = (t & 3) ^ ((t >> 3) & 3);
        b_src[k] = (bn * 192 + row) * 32 + c * 8;
    }
    const int wdst = wv * 512;

    int aoff[2], boff[6];
    #pragma unroll
    for (int i = 0; i < 2; ++i) {
        int row = wm + 16 * i + lr;
        aoff[i] = (row * 4 + (lg ^ ((row >> 1) & 3))) * 8;
    }
    #pragma unroll
    for (int j = 0; j < 6; ++j) {
        int row = wn + 16 * j + lr;
        boff[j] = (row * 4 + (lg ^ ((row >> 1) & 3))) * 8;
    }

    f32x4 acc[2][6] = {};

    #pragma unroll
    for (int s = 0; s < NS; ++s) {
        const int k6 = (s < 6) ? s : s - 6;
        const ushort* AHp = (!DUAL || s < 6) ? Ah1 : Ah2;
        const ushort* BHp = (!DUAL || s < 6) ? Bh1 : Bh2;
        const long long asb = (long long)k6 * SS;
        const int bsb = k6 * (NC * 32);

        gld16(AHp + asb + a_src, AHs + wdst);
        #pragma unroll
        for (int k = 0; k < 3; ++k)
            gld16(BHp + bsb + b_src[k], BHs + k * 2048 + wdst);
        __syncthreads();   // drain vmcnt -> tile visible

        f16x8 ah[2];
        #pragma unroll
        for (int i = 0; i < 2; ++i)
            ah[i] = *(const f16x8*)&AHs[aoff[i]];
        #pragma unroll
        for (int j = 0; j < 6; ++j) {
            f16x8 bh = *(const f16x8*)&BHs[boff[j]];
            #pragma unroll
            for (int i = 0; i < 2; ++i)
                acc[i][j] = __builtin_amdgcn_mfma_f32_16x16x32_f16(ah[i], bh, acc[i][j], 0, 0, 0);
        }
        __syncthreads();   // all reads done before next stage overwrites
    }

    #pragma unroll
    for (int j = 0; j < 6; ++j) {
        const int c = bn * 192 + wn + 16 * j + lr;
        const float bv = bias ? bias[c] : 0.f;
        #pragma unroll
        for (int i = 0; i < 2; ++i)
            #pragma unroll
            for (int r = 0; r < 4; ++r) {
                int m = bm * 64 + wm + 16 * i + 4 * lg + r;
                if (m < M) {
                    float f = acc[i][j][r] + bv;
                    if constexpr (F32OUT) {
                        int b2 = m / 49, r2 = m - b2 * 49;
                        outF[(long long)b2 * out_bs + r2 * 192 + c] = f;
                    } else {
                        long long o = (long long)(c >> 5) * SS + (long long)m * 32 + (c & 31);
                        outH[o] = f16u(f);
                    }
                }
            }
    }
}

// ---------------------------------------------------------------------------
// MFMA differential attention on K-slabbed fp16 planes. One (batch,head)
// per block, 4 waves; swapped QK^T -> lane-local softmax; V staged to LDS
// transposed ([d][j], pad 70); wave-private P LDS; single barrier.
// ---------------------------------------------------------------------------
__global__ __launch_bounds__(256, 4) void attn_f16(
    const ushort* __restrict__ qT, const ushort* __restrict__ kT,
    const ushort* __restrict__ vT,
    const ushort* __restrict__ qR, const ushort* __restrict__ kR,
    const ushort* __restrict__ vR,
    long long SS,
    const float* __restrict__ rpb, const float* __restrict__ lam_ptr,
    ushort* __restrict__ otH, ushort* __restrict__ orH)
{
    __shared__ __align__(16) ushort Pth[64][72];
    __shared__ __align__(16) ushort Vs[2][32][70];  // [stream][d][j]
    __shared__ float bias_s[169];

    const int tid = threadIdx.x;
    const int bb = blockIdx.x / 6;
    const int h  = blockIdx.x - bb * 6;
    const int lane = tid & 63;
    const int w  = tid >> 6;
    const int li = lane & 15;
    const int lg = lane >> 4;
    const long long rowbase = (long long)bb * 49 * 32;
    const long long hb = (long long)h * SS + rowbase;

    for (int idx = tid; idx < 169; idx += 256) bias_s[idx] = rpb[idx * 6 + h];

    // ---- stage V transposed into LDS ----
    {
        const ushort* vsrc[2] = {vT + hb, vR + hb};
        for (int c = tid; c < 392; c += 256) {
            int s  = c / 196;
            int r2 = c - s * 196;
            int j  = r2 >> 2;
            int d4 = (r2 & 3) * 8;
            u16x8 v = *(const u16x8*)(vsrc[s] + j * 32 + d4);
            #pragma unroll
            for (int e = 0; e < 8; ++e) Vs[s][d4 + e][j] = v[e];
        }
        for (int c = tid; c < 2 * 32 * 21; c += 256) {
            int s  = c / (32 * 21);
            int r1 = c - s * (32 * 21);
            int d  = r1 / 21;
            int j  = 49 + (r1 - d * 21);
            Vs[s][d][j] = 0;
        }
    }

    float lraw = lam_ptr[0];
    float lam = 1.f / (1.f + __expf(-lraw));
    lam = fminf(fmaxf(lam, 0.01f), 0.99f);

    const int irow = min(w * 16 + li, 48);

    f32x4 st[2][4];
    #pragma unroll
    for (int s = 0; s < 2; ++s) {
        const ushort* qb = (s ? qR : qT) + hb;
        const ushort* kb = (s ? kR : kT) + hb;
        f16x8 qh = *(const f16x8*)(qb + irow * 32 + 8 * lg);
        #pragma unroll
        for (int jt = 0; jt < 4; ++jt) {
            int jr = jt * 16 + li; if (jr > 48) jr = 48;
            f16x8 kh = *(const f16x8*)(kb + jr * 32 + 8 * lg);
            f32x4 c = {};
            c = __builtin_amdgcn_mfma_f32_16x16x32_f16(kh, qh, c, 0, 0, 0);
            st[s][jt] = c;
        }
    }
    __syncthreads();   // bias_s + Vs staged (only barrier)

    const int ri = (irow * 9363) >> 16;
    const int ci = irow - 7 * ri;
    float bias_v[4][4];
    #pragma unroll
    for (int jt = 0; jt < 4; ++jt)
        #pragma unroll
        for (int r = 0; r < 4; ++r) {
            int j = jt * 16 + 4 * lg + r;
            int jc = (j < 49) ? j : 48;
            int rj = (jc * 9363) >> 16;
            int cj = jc - 7 * rj;
            bias_v[jt][r] = bias_s[(ri - rj + 6) * 13 + (ci - cj + 6)];
        }

    float p[2][4][4];
    #pragma unroll
    for (int s = 0; s < 2; ++s) {
        float m = -1e30f;
        #pragma unroll
        for (int jt = 0; jt < 4; ++jt)
            #pragma unroll
            for (int r = 0; r < 4; ++r) {
                int j = jt * 16 + 4 * lg + r;
                float sv = (j < 49) ? (st[s][jt][r] * SCALE_ + bias_v[jt][r]) : -1e30f;
                p[s][jt][r] = sv;
                m = fmaxf(m, sv);
            }
        m = fmaxf(m, __shfl_xor(m, 16));
        m = fmaxf(m, __shfl_xor(m, 32));
        float sum = 0.f;
        #pragma unroll
        for (int jt = 0; jt < 4; ++jt)
            #pragma unroll
            for (int r = 0; r < 4; ++r) {
                float e = __expf(p[s][jt][r] - m);
                p[s][jt][r] = e;
                sum += e;
            }
        sum += __shfl_xor(sum, 16);
        sum += __shfl_xor(sum, 32);
        float inv = 1.f / sum;
        #pragma unroll
        for (int jt = 0; jt < 4; ++jt)
            #pragma unroll
            for (int r = 0; r < 4; ++r)
                p[s][jt][r] *= inv;
    }

    const int prow = w * 16 + li;
    #pragma unroll
    for (int s = 0; s < 2; ++s) {
        #pragma unroll
        for (int jt = 0; jt < 4; ++jt) {
            ushort4 h4;
            #pragma unroll
            for (int r = 0; r < 4; ++r) {
                float at = p[0][jt][r], ar = p[1][jt][r];
                float f = (s == 0) ? (at - lam * ar) : (ar - lam * at);
                ((ushort*)&h4)[r] = f16u(f);
            }
            *(ushort4*)&Pth[prow][jt * 16 + 4 * lg] = h4;
        }

        f32x4 acc[2] = {};
        #pragma unroll
        for (int ks = 0; ks < 2; ++ks) {
            f16x8 pa = *(const f16x8*)&Pth[prow][ks * 32 + 8 * lg];
            #pragma unroll
            for (int dt = 0; dt < 2; ++dt) {
                f16x8 vh = *(const f16x8*)&Vs[s][dt * 16 + li][ks * 32 + 8 * lg];
                acc[dt] = __builtin_amdgcn_mfma_f32_16x16x32_f16(pa, vh, acc[dt], 0, 0, 0);
            }
        }
        ushort* oph = s ? orH : otH;
        #pragma unroll
        for (int dt = 0; dt < 2; ++dt)
            #pragma unroll
            for (int r = 0; r < 4; ++r) {
                int i = w * 16 + 4 * lg + r;
                if (i < 49) {
                    long long o = (long long)h * SS + rowbase + (long long)i * 32 + dt * 16 + li;
                    oph[o] = f16u(acc[dt][r]);
                }
            }
    }
}

// ---------------------------------------------------------------------------
extern "C" void kernel_launch(void* const* d_in, const int* in_sizes, int n_in,
                              void* d_out, int out_size, void* d_ws, size_t ws_size,
                              hipStream_t stream)
{
    const float* x_sa      = (const float*)d_in[0];
    const float* x_ca      = (const float*)d_in[1];
    const float* lam_sa    = (const float*)d_in[2];
    const float* lam_ca    = (const float*)d_in[3];
    const float* sa_enh    = (const float*)d_in[4];
    const float* ca_enh    = (const float*)d_in[5];
    const float* W_sa_qkv  = (const float*)d_in[6];
    const float* b_sa_qkv  = (const float*)d_in[7];
    const float* W_sa_ct   = (const float*)d_in[8];
    const float* W_sa_cr   = (const float*)d_in[9];
    const float* W_ca_q    = (const float*)d_in[10];
    const float* b_ca_q    = (const float*)d_in[11];
    const float* W_ca_kv   = (const float*)d_in[12];
    const float* b_ca_kv   = (const float*)d_in[13];
    const float* W_ca_ct   = (const float*)d_in[14];
    const float* W_ca_cr   = (const float*)d_in[15];
    const float* rpb       = (const float*)d_in[16];
    const float* W_proj_sa = (const float*)d_in[17];
    const float* b_proj_sa = (const float*)d_in[18];
    const float* W_proj_ca = (const float*)d_in[19];
    const float* b_proj_ca = (const float*)d_in[20];
    float* out = (float*)d_out;
    float* ws  = (float*)d_ws;

    // ---- f32 combined-weight temps ----
    float* CW0 = ws;             // 192x576
    float* CW1 = CW0 + 110592;
    float* CW2 = CW1 + 110592;   // 192x192
    float* CW3 = CW2 + 36864;
    float* CW4 = CW3 + 36864;    // 192x384
    float* CW5 = CW4 + 73728;

    smallmm_kernel<<<108, 256, 0, stream>>>(W_sa_cr, W_sa_qkv, sa_enh, CW0, 576);
    smallmm_kernel<<<108, 256, 0, stream>>>(W_sa_ct, W_sa_qkv, sa_enh, CW1, 576);
    smallmm_kernel<<< 36, 256, 0, stream>>>(W_ca_cr, W_ca_q,   ca_enh, CW2, 192);
    smallmm_kernel<<< 36, 256, 0, stream>>>(W_ca_ct, W_ca_q,   ca_enh, CW3, 192);
    smallmm_kernel<<< 72, 256, 0, stream>>>(W_ca_cr, W_ca_kv,  ca_enh, CW4, 384);
    smallmm_kernel<<< 72, 256, 0, stream>>>(W_ca_ct, W_ca_kv,  ca_enh, CW5, 384);

    // ---- K-slabbed fp16 weights (single plane each) ----
    ushort* wb = (ushort*)(ws + 442368);
    ushort* WsaqH = wb;                  // 110592
    ushort* C0H  = WsaqH + 110592;
    ushort* C1H  = C0H + 110592;
    ushort* WcqH = C1H + 110592;         // 36864
    ushort* C2H  = WcqH + 36864;
    ushort* C3H  = C2H + 36864;
    ushort* WckH = C3H + 36864;          // 73728
    ushort* C4H  = WckH + 73728;
    ushort* C5H  = C4H + 73728;
    ushort* WpsH = C5H + 73728;          // 36864
    ushort* WpcH = WpsH + 36864;
    ushort* chunkU = WpcH + 36864;       // = wb + 737280

    conv_wT<<<432, 256, 0, stream>>>(W_sa_qkv, 576, WsaqH);
    conv_wT<<<432, 256, 0, stream>>>(CW0,      576, C0H);
    conv_wT<<<432, 256, 0, stream>>>(CW1,      576, C1H);
    conv_wT<<<144, 256, 0, stream>>>(W_ca_q,   192, WcqH);
    conv_wT<<<144, 256, 0, stream>>>(CW2,      192, C2H);
    conv_wT<<<144, 256, 0, stream>>>(CW3,      192, C3H);
    conv_wT<<<288, 256, 0, stream>>>(W_ca_kv,  384, WckH);
    conv_wT<<<288, 256, 0, stream>>>(CW4,      384, C4H);
    conv_wT<<<288, 256, 0, stream>>>(CW5,      384, C5H);
    conv_wT<<<144, 256, 0, stream>>>(W_proj_sa,192, WpsH);
    conv_wT<<<144, 256, 0, stream>>>(W_proj_ca,192, WpcH);

    // ---- chunking: 188160 bytes per batch element, 64KB tail pad ----
    long long avail = (long long)ws_size - 442368LL * 4 - 737280LL * 2 - 65536;
    int cbmax = (int)(avail / 188160);
    if (cbmax > 2048) cbmax = 2048;
    if (cbmax < 1) cbmax = 1;

    const long long OUT1 = 2LL * 2048 * 49 * 192;
    dim3 blk(256);

    for (int c0 = 0; c0 < 2048; c0 += cbmax) {
        int cb = (c0 + cbmax <= 2048) ? cbmax : (2048 - c0);
        int M = cb * 49;
        long long SS = (long long)M * 32;
        int gy = (M + 63) / 64;
        int cblk = (int)(((long long)M * 24 + 255) / 256);
        if (cblk > 4096) cblk = 4096;

        dim3 g1(3, gy), g2(1, gy), g3(2, gy);

        // =========================== SA branch ===========================
        ushort* XtH = chunkU;                              // [6][M][32]
        ushort* XrH = XtH + (long long)cbmax * 9408;
        ushort* QtH = XrH + (long long)cbmax * 9408;       // [18][M][32]
        ushort* QrH = QtH + (long long)cbmax * 28224;
        ushort* OtH = QrH + (long long)cbmax * 28224;      // [6][M][32]
        ushort* OrH = OtH + (long long)cbmax * 9408;

        conv_x<<<cblk, blk, 0, stream>>>(x_sa + (long long)c0 * 9408, 9408, XtH, M);
        conv_x<<<cblk, blk, 0, stream>>>(x_sa + (2048LL + c0) * 9408, 9408, XrH, M);

        gemm_f16<576, true, false><<<g1, blk, 0, stream>>>(
            XtH, XrH, WsaqH, C0H, b_sa_qkv, QtH, nullptr, 0, M);
        gemm_f16<576, true, false><<<g1, blk, 0, stream>>>(
            XrH, XtH, WsaqH, C1H, b_sa_qkv, QrH, nullptr, 0, M);

        attn_f16<<<cb * 6, blk, 0, stream>>>(
            QtH, QtH + 6 * SS, QtH + 12 * SS,
            QrH, QrH + 6 * SS, QrH + 12 * SS,
            SS, rpb, lam_sa, OtH, OrH);

        gemm_f16<192, false, true><<<g2, blk, 0, stream>>>(
            OtH, nullptr, WpsH, nullptr, b_proj_sa, nullptr,
            out + (long long)c0 * 9408, 9408, M);
        gemm_f16<192, false, true><<<g2, blk, 0, stream>>>(
            OrH, nullptr, WpsH, nullptr, b_proj_sa, nullptr,
            out + (2048LL + c0) * 9408, 9408, M);

        // =========================== CA branch ===========================
        ushort* CXtH = chunkU;                             // [6][M][32]
        ushort* CXrH = CXtH + (long long)cbmax * 9408;
        ushort* CQtH = CXrH + (long long)cbmax * 9408;     // [6][M][32]
        ushort* CQrH = CQtH + (long long)cbmax * 9408;
        ushort* KtH  = CQrH + (long long)cbmax * 9408;     // [12][M][32]
        ushort* KrH  = KtH + (long long)cbmax * 18816;
        ushort* COtH = KrH + (long long)cbmax * 18816;     // [6][M][32]
        ushort* COrH = COtH + (long long)cbmax * 9408;

        conv_x<<<cblk, blk, 0, stream>>>(x_ca + (long long)c0 * 18816, 18816, CXtH, M);
        conv_x<<<cblk, blk, 0, stream>>>(x_ca + (long long)c0 * 18816 + 9408, 18816, CXrH, M);

        gemm_f16<192, true, false><<<g2, blk, 0, stream>>>(
            CXtH, CXrH, WcqH, C2H, b_ca_q, CQtH, nullptr, 0, M);
        gemm_f16<192, true, false><<<g2, blk, 0, stream>>>(
            CXrH, CXtH, WcqH, C3H, b_ca_q, CQrH, nullptr, 0, M);

        gemm_f16<384, true, false><<<g3, blk, 0, stream>>>(
            CXtH, CXrH, WckH, C4H, b_ca_kv, KtH, nullptr, 0, M);
        gemm_f16<384, true, false><<<g3, blk, 0, stream>>>(
            CXrH, CXtH, WckH, C5H, b_ca_kv, KrH, nullptr, 0, M);

        attn_f16<<<cb * 6, blk, 0, stream>>>(
            CQtH, KtH, KtH + 6 * SS,
            CQrH, KrH, KrH + 6 * SS,
            SS, rpb, lam_ca, COtH, COrH);

        gemm_f16<192, false, true><<<g2, blk, 0, stream>>>(
            COtH, nullptr, WpcH, nullptr, b_proj_ca, nullptr,
            out + OUT1 + (long long)c0 * 18816, 18816, M);
        gemm_f16<192, false, true><<<g2, blk, 0, stream>>>(
            COrH, nullptr, WpcH, nullptr, b_proj_ca, nullptr,
            out + OUT1 + (long long)c0 * 18816 + 9408, 18816, M);
    }
}

// Round 11
// 795.716 us; speedup vs baseline: 2.8791x; 1.1287x over previous
//
#include <hip/hip_runtime.h>
#include <cmath>

static constexpr float SCALE_ = 0.17677669529663687f; // 32^-0.5

typedef __attribute__((ext_vector_type(8))) _Float16 f16x8;
typedef __attribute__((ext_vector_type(8))) ushort u16x8;
typedef __attribute__((ext_vector_type(4))) float f32x4;

__device__ inline ushort f16u(float f) {
    union { _Float16 h; ushort u; } c;
    c.h = (_Float16)f;
    return c.u;
}

// async global->LDS, 16B per lane; LDS dest = wave-uniform base + lane*16
__device__ __forceinline__ void gld16(const ushort* g, ushort* l) {
    __builtin_amdgcn_global_load_lds(
        (const __attribute__((address_space(1))) unsigned int*)g,
        (__attribute__((address_space(3))) unsigned int*)l,
        16, 0, 0);
}

// ---------------------------------------------------------------------------
// Fused weight-combine: all 6 small GEMMs in one launch (job table).
// ---------------------------------------------------------------------------
struct SmallmmJobs {
    const float* Wa[6];
    const float* Wb[6];
    const float* sc[6];
    float*       out[6];
    int          NCb[6];
    int          base[7];
};
__global__ __launch_bounds__(256) void smallmm_all(SmallmmJobs J)
{
    int b = blockIdx.x;
    int j = 0;
    #pragma unroll
    for (int k = 1; k < 6; ++k) if (b >= J.base[k]) j = k;
    int idx = (b - J.base[j]) * 256 + threadIdx.x;
    int NCb = J.NCb[j];
    int n4  = NCb >> 2;
    int m   = idx / n4;
    int n0  = (idx - m * n4) << 2;
    if (m >= 192) return;
    const float* Wa = J.Wa[j];
    const float* Wb = J.Wb[j];
    float s = J.sc[j][0];
    float ax = 0.f, ay = 0.f, az = 0.f, aw = 0.f;
    for (int k = 0; k < 192; ++k) {
        float a = Wa[m * 192 + k];
        const float4 bv = *(const float4*)(Wb + (size_t)k * NCb + n0);
        ax += a * bv.x; ay += a * bv.y; az += a * bv.z; aw += a * bv.w;
    }
    float4 r = make_float4(ax * s, ay * s, az * s, aw * s);
    *(float4*)(J.out[j] + (size_t)m * NCb + n0) = r;
}

// ---------------------------------------------------------------------------
// Fused weight transpose+convert: all 11 weights in one launch.
// f32 [192][NC] -> K-slabbed transposed fp16 [6][NC][32]
// ---------------------------------------------------------------------------
struct WtJobs {
    const float* W[11];
    ushort*      dh[11];
    int          NC[11];
    int          base[12];
};
__global__ __launch_bounds__(256) void conv_wT_all(WtJobs J)
{
    int b = blockIdx.x;
    int j = 0;
    #pragma unroll
    for (int k = 1; k < 11; ++k) if (b >= J.base[k]) j = k;
    int idx = (b - J.base[j]) * 256 + threadIdx.x;
    int NC = J.NC[j];
    if (idx >= NC * 192) return;
    int n = idx / 192, k = idx - n * 192;
    float f = J.W[j][(long long)k * NC + n];
    long long o = ((long long)(k >> 5) * NC + n) * 32 + (k & 31);
    J.dh[j][o] = f16u(f);
}

// ---------------------------------------------------------------------------
// Activation f32 -> K-slabbed fp16 [6][Mc][32]; handles BOTH streams (t,r).
// ---------------------------------------------------------------------------
__global__ __launch_bounds__(256) void conv_x2(
    const float* __restrict__ src_t, const float* __restrict__ src_r,
    long long src_bs,
    ushort* __restrict__ dh_t, ushort* __restrict__ dh_r, int Mc)
{
    const long long SS = (long long)Mc * 32;
    const long long total8 = (long long)Mc * 24;
    for (long long t = (long long)blockIdx.x * 256 + threadIdx.x; t < 2 * total8;
         t += (long long)gridDim.x * 256) {
        const int second = (t >= total8);
        long long ti = second ? t - total8 : t;
        const float* src = second ? src_r : src_t;
        ushort* dh = second ? dh_r : dh_t;
        int m  = (int)(ti / 24);
        int c8 = (int)(ti - (long long)m * 24) * 8;
        int bb = m / 49, r = m - bb * 49;
        const float* sp = src + (long long)bb * src_bs + r * 192 + c8;
        float4 v0 = *(const float4*)sp;
        float4 v1 = *(const float4*)(sp + 4);
        float f[8] = {v0.x, v0.y, v0.z, v0.w, v1.x, v1.y, v1.z, v1.w};
        u16x8 h8;
        #pragma unroll
        for (int e = 0; e < 8; ++e) h8[e] = f16u(f[e]);
        long long o = (long long)(c8 >> 5) * SS + (long long)m * 32 + (c8 & 31);
        *(u16x8*)(dh + o) = h8;
    }
}

// ---------------------------------------------------------------------------
// m97-structure fp16 MFMA GEMM, BK=64 (two 32-K slabs per barrier pair),
// PAIRED launches (blockIdx.z selects job a/b; B1 shared across pair).
// A: [6][M][32] fp16; W: [6][NC][32] fp16. Per phase: stage 2 slabs of
// A(64x32)+B(192x32) via global_load_lds w16 (linear dest, src chunk
// c ^= (row>>1)&3, same XOR on ds_read -> 0 conflicts, r7-verified).
// Block 64M x 192N, 4 waves, wave 32x96.
// F32OUT: f32 scatter (b2=m/49, row stride 192); else slabbed fp16 out.
// A stage may overread past plane tail; launcher pads workspace 64KB.
// ---------------------------------------------------------------------------
template<int NC, bool DUAL, bool F32OUT>
__global__ __launch_bounds__(256, 4) void gemm_f16(
    const ushort* __restrict__ A1a, const ushort* __restrict__ A2a,
    const ushort* __restrict__ B2a, ushort* __restrict__ outHa,
    float* __restrict__ outFa,
    const ushort* __restrict__ A1b, const ushort* __restrict__ A2b,
    const ushort* __restrict__ B2b, ushort* __restrict__ outHb,
    float* __restrict__ outFb,
    const ushort* __restrict__ B1, const float* __restrict__ bias,
    long long out_bs, int M)
{
    __shared__ __align__(16) ushort AHs[2][2048];   // 2 slabs x 64 x 32
    __shared__ __align__(16) ushort BHs[2][6144];   // 2 slabs x 192 x 32

    const int z = blockIdx.z;
    const ushort* Ah1 = z ? A1b : A1a;
    const ushort* Ah2 = z ? A2b : A2a;
    const ushort* Bh2 = z ? B2b : B2a;

    const int tid = threadIdx.x;
    const int lane = tid & 63, wv = tid >> 6;
    const int wm = (wv >> 1) * 32;
    const int wn = (wv & 1) * 96;
    const int lr = lane & 15, lg = lane >> 4;
    const int bn = blockIdx.x, bm = blockIdx.y;
    const long long SS = (long long)M * 32;
    constexpr int NP = DUAL ? 6 : 3;   // phases of 2 slabs

    const int at_row = tid >> 2;
    const int at_c   = (tid & 3) ^ ((tid >> 3) & 3);
    const long long a_src = (long long)(bm * 64 + at_row) * 32 + at_c * 8;
    int b_src[3];
    #pragma unroll
    for (int k = 0; k < 3; ++k) {
        int t = k * 256 + tid;
        int row = t >> 2, c = (t & 3) ^ ((t >> 3) & 3);
        b_src[k] = (bn * 192 + row) * 32 + c * 8;
    }
    const int wdst = wv * 512;

    int aoff[2], boff[6];
    #pragma unroll
    for (int i = 0; i < 2; ++i) {
        int row = wm + 16 * i + lr;
        aoff[i] = (row * 4 + (lg ^ ((row >> 1) & 3))) * 8;
    }
    #pragma unroll
    for (int j = 0; j < 6; ++j) {
        int row = wn + 16 * j + lr;
        boff[j] = (row * 4 + (lg ^ ((row >> 1) & 3))) * 8;
    }

    f32x4 acc[2][6] = {};

    #pragma unroll
    for (int p = 0; p < NP; ++p) {
        // stage two slabs into the two LDS halves
        #pragma unroll
        for (int hbf = 0; hbf < 2; ++hbf) {
            const int s = 2 * p + hbf;
            const int k6 = (s < 6) ? s : s - 6;
            const ushort* AHp = (!DUAL || s < 6) ? Ah1 : Ah2;
            const ushort* BHp = (!DUAL || s < 6) ? B1  : Bh2;
            const long long asb = (long long)k6 * SS;
            const int bsb = k6 * (NC * 32);
            gld16(AHp + asb + a_src, AHs[hbf] + wdst);
            #pragma unroll
            for (int k = 0; k < 3; ++k)
                gld16(BHp + bsb + b_src[k], BHs[hbf] + k * 2048 + wdst);
        }
        __syncthreads();   // drain vmcnt -> both slabs visible

        #pragma unroll
        for (int hbf = 0; hbf < 2; ++hbf) {
            f16x8 ah[2];
            #pragma unroll
            for (int i = 0; i < 2; ++i)
                ah[i] = *(const f16x8*)&AHs[hbf][aoff[i]];
            #pragma unroll
            for (int j = 0; j < 6; ++j) {
                f16x8 bh = *(const f16x8*)&BHs[hbf][boff[j]];
                #pragma unroll
                for (int i = 0; i < 2; ++i)
                    acc[i][j] = __builtin_amdgcn_mfma_f32_16x16x32_f16(ah[i], bh, acc[i][j], 0, 0, 0);
            }
        }
        __syncthreads();   // all reads done before next stage overwrites
    }

    #pragma unroll
    for (int j = 0; j < 6; ++j) {
        const int c = bn * 192 + wn + 16 * j + lr;
        const float bv = bias ? bias[c] : 0.f;
        #pragma unroll
        for (int i = 0; i < 2; ++i)
            #pragma unroll
            for (int r = 0; r < 4; ++r) {
                int m = bm * 64 + wm + 16 * i + 4 * lg + r;
                if (m < M) {
                    float f = acc[i][j][r] + bv;
                    if constexpr (F32OUT) {
                        float* outF = z ? outFb : outFa;
                        int b2 = m / 49, r2 = m - b2 * 49;
                        outF[(long long)b2 * out_bs + r2 * 192 + c] = f;
                    } else {
                        ushort* outH = z ? outHb : outHa;
                        long long o = (long long)(c >> 5) * SS + (long long)m * 32 + (c & 31);
                        outH[o] = f16u(f);
                    }
                }
            }
    }
}

// ---------------------------------------------------------------------------
// MFMA differential attention on K-slabbed fp16 planes (r10-verified).
// ---------------------------------------------------------------------------
__global__ __launch_bounds__(256, 4) void attn_f16(
    const ushort* __restrict__ qT, const ushort* __restrict__ kT,
    const ushort* __restrict__ vT,
    const ushort* __restrict__ qR, const ushort* __restrict__ kR,
    const ushort* __restrict__ vR,
    long long SS,
    const float* __restrict__ rpb, const float* __restrict__ lam_ptr,
    ushort* __restrict__ otH, ushort* __restrict__ orH)
{
    __shared__ __align__(16) ushort Pth[64][72];
    __shared__ __align__(16) ushort Vs[2][32][70];  // [stream][d][j]
    __shared__ float bias_s[169];

    const int tid = threadIdx.x;
    const int bb = blockIdx.x / 6;
    const int h  = blockIdx.x - bb * 6;
    const int lane = tid & 63;
    const int w  = tid >> 6;
    const int li = lane & 15;
    const int lg = lane >> 4;
    const long long rowbase = (long long)bb * 49 * 32;
    const long long hb = (long long)h * SS + rowbase;

    for (int idx = tid; idx < 169; idx += 256) bias_s[idx] = rpb[idx * 6 + h];

    {
        const ushort* vsrc[2] = {vT + hb, vR + hb};
        for (int c = tid; c < 392; c += 256) {
            int s  = c / 196;
            int r2 = c - s * 196;
            int j  = r2 >> 2;
            int d4 = (r2 & 3) * 8;
            u16x8 v = *(const u16x8*)(vsrc[s] + j * 32 + d4);
            #pragma unroll
            for (int e = 0; e < 8; ++e) Vs[s][d4 + e][j] = v[e];
        }
        for (int c = tid; c < 2 * 32 * 21; c += 256) {
            int s  = c / (32 * 21);
            int r1 = c - s * (32 * 21);
            int d  = r1 / 21;
            int j  = 49 + (r1 - d * 21);
            Vs[s][d][j] = 0;
        }
    }

    float lraw = lam_ptr[0];
    float lam = 1.f / (1.f + __expf(-lraw));
    lam = fminf(fmaxf(lam, 0.01f), 0.99f);

    const int irow = min(w * 16 + li, 48);

    f32x4 st[2][4];
    #pragma unroll
    for (int s = 0; s < 2; ++s) {
        const ushort* qb = (s ? qR : qT) + hb;
        const ushort* kb = (s ? kR : kT) + hb;
        f16x8 qh = *(const f16x8*)(qb + irow * 32 + 8 * lg);
        #pragma unroll
        for (int jt = 0; jt < 4; ++jt) {
            int jr = jt * 16 + li; if (jr > 48) jr = 48;
            f16x8 kh = *(const f16x8*)(kb + jr * 32 + 8 * lg);
            f32x4 c = {};
            c = __builtin_amdgcn_mfma_f32_16x16x32_f16(kh, qh, c, 0, 0, 0);
            st[s][jt] = c;
        }
    }
    __syncthreads();   // bias_s + Vs staged (only barrier)

    const int ri = (irow * 9363) >> 16;
    const int ci = irow - 7 * ri;
    float bias_v[4][4];
    #pragma unroll
    for (int jt = 0; jt < 4; ++jt)
        #pragma unroll
        for (int r = 0; r < 4; ++r) {
            int j = jt * 16 + 4 * lg + r;
            int jc = (j < 49) ? j : 48;
            int rj = (jc * 9363) >> 16;
            int cj = jc - 7 * rj;
            bias_v[jt][r] = bias_s[(ri - rj + 6) * 13 + (ci - cj + 6)];
        }

    float p[2][4][4];
    #pragma unroll
    for (int s = 0; s < 2; ++s) {
        float m = -1e30f;
        #pragma unroll
        for (int jt = 0; jt < 4; ++jt)
            #pragma unroll
            for (int r = 0; r < 4; ++r) {
                int j = jt * 16 + 4 * lg + r;
                float sv = (j < 49) ? (st[s][jt][r] * SCALE_ + bias_v[jt][r]) : -1e30f;
                p[s][jt][r] = sv;
                m = fmaxf(m, sv);
            }
        m = fmaxf(m, __shfl_xor(m, 16));
        m = fmaxf(m, __shfl_xor(m, 32));
        float sum = 0.f;
        #pragma unroll
        for (int jt = 0; jt < 4; ++jt)
            #pragma unroll
            for (int r = 0; r < 4; ++r) {
                float e = __expf(p[s][jt][r] - m);
                p[s][jt][r] = e;
                sum += e;
            }
        sum += __shfl_xor(sum, 16);
        sum += __shfl_xor(sum, 32);
        float inv = 1.f / sum;
        #pragma unroll
        for (int jt = 0; jt < 4; ++jt)
            #pragma unroll
            for (int r = 0; r < 4; ++r)
                p[s][jt][r] *= inv;
    }

    const int prow = w * 16 + li;
    #pragma unroll
    for (int s = 0; s < 2; ++s) {
        #pragma unroll
        for (int jt = 0; jt < 4; ++jt) {
            ushort4 h4;
            #pragma unroll
            for (int r = 0; r < 4; ++r) {
                float at = p[0][jt][r], ar = p[1][jt][r];
                float f = (s == 0) ? (at - lam * ar) : (ar - lam * at);
                ((ushort*)&h4)[r] = f16u(f);
            }
            *(ushort4*)&Pth[prow][jt * 16 + 4 * lg] = h4;
        }

        f32x4 acc[2] = {};
        #pragma unroll
        for (int ks = 0; ks < 2; ++ks) {
            f16x8 pa = *(const f16x8*)&Pth[prow][ks * 32 + 8 * lg];
            #pragma unroll
            for (int dt = 0; dt < 2; ++dt) {
                f16x8 vh = *(const f16x8*)&Vs[s][dt * 16 + li][ks * 32 + 8 * lg];
                acc[dt] = __builtin_amdgcn_mfma_f32_16x16x32_f16(pa, vh, acc[dt], 0, 0, 0);
            }
        }
        ushort* oph = s ? orH : otH;
        #pragma unroll
        for (int dt = 0; dt < 2; ++dt)
            #pragma unroll
            for (int r = 0; r < 4; ++r) {
                int i = w * 16 + 4 * lg + r;
                if (i < 49) {
                    long long o = (long long)h * SS + rowbase + (long long)i * 32 + dt * 16 + li;
                    oph[o] = f16u(acc[dt][r]);
                }
            }
    }
}

// ---------------------------------------------------------------------------
extern "C" void kernel_launch(void* const* d_in, const int* in_sizes, int n_in,
                              void* d_out, int out_size, void* d_ws, size_t ws_size,
                              hipStream_t stream)
{
    const float* x_sa      = (const float*)d_in[0];
    const float* x_ca      = (const float*)d_in[1];
    const float* lam_sa    = (const float*)d_in[2];
    const float* lam_ca    = (const float*)d_in[3];
    const float* sa_enh    = (const float*)d_in[4];
    const float* ca_enh    = (const float*)d_in[5];
    const float* W_sa_qkv  = (const float*)d_in[6];
    const float* b_sa_qkv  = (const float*)d_in[7];
    const float* W_sa_ct   = (const float*)d_in[8];
    const float* W_sa_cr   = (const float*)d_in[9];
    const float* W_ca_q    = (const float*)d_in[10];
    const float* b_ca_q    = (const float*)d_in[11];
    const float* W_ca_kv   = (const float*)d_in[12];
    const float* b_ca_kv   = (const float*)d_in[13];
    const float* W_ca_ct   = (const float*)d_in[14];
    const float* W_ca_cr   = (const float*)d_in[15];
    const float* rpb       = (const float*)d_in[16];
    const float* W_proj_sa = (const float*)d_in[17];
    const float* b_proj_sa = (const float*)d_in[18];
    const float* W_proj_ca = (const float*)d_in[19];
    const float* b_proj_ca = (const float*)d_in[20];
    float* out = (float*)d_out;
    float* ws  = (float*)d_ws;

    // ---- f32 combined-weight temps ----
    float* CW0 = ws;             // 192x576
    float* CW1 = CW0 + 110592;
    float* CW2 = CW1 + 110592;   // 192x192
    float* CW3 = CW2 + 36864;
    float* CW4 = CW3 + 36864;    // 192x384
    float* CW5 = CW4 + 73728;

    {
        SmallmmJobs J;
        J.Wa[0]=W_sa_cr; J.Wb[0]=W_sa_qkv; J.sc[0]=sa_enh; J.out[0]=CW0; J.NCb[0]=576;
        J.Wa[1]=W_sa_ct; J.Wb[1]=W_sa_qkv; J.sc[1]=sa_enh; J.out[1]=CW1; J.NCb[1]=576;
        J.Wa[2]=W_ca_cr; J.Wb[2]=W_ca_q;   J.sc[2]=ca_enh; J.out[2]=CW2; J.NCb[2]=192;
        J.Wa[3]=W_ca_ct; J.Wb[3]=W_ca_q;   J.sc[3]=ca_enh; J.out[3]=CW3; J.NCb[3]=192;
        J.Wa[4]=W_ca_cr; J.Wb[4]=W_ca_kv;  J.sc[4]=ca_enh; J.out[4]=CW4; J.NCb[4]=384;
        J.Wa[5]=W_ca_ct; J.Wb[5]=W_ca_kv;  J.sc[5]=ca_enh; J.out[5]=CW5; J.NCb[5]=384;
        int bs[7] = {0,108,216,252,288,360,432};
        for (int i = 0; i < 7; ++i) J.base[i] = bs[i];
        smallmm_all<<<432, 256, 0, stream>>>(J);
    }

    // ---- K-slabbed fp16 weights ----
    ushort* wb = (ushort*)(ws + 442368);
    ushort* WsaqH = wb;
    ushort* C0H  = WsaqH + 110592;
    ushort* C1H  = C0H + 110592;
    ushort* WcqH = C1H + 110592;
    ushort* C2H  = WcqH + 36864;
    ushort* C3H  = C2H + 36864;
    ushort* WckH = C3H + 36864;
    ushort* C4H  = WckH + 73728;
    ushort* C5H  = C4H + 73728;
    ushort* WpsH = C5H + 73728;
    ushort* WpcH = WpsH + 36864;
    ushort* chunkU = WpcH + 36864;       // = wb + 737280

    {
        WtJobs J;
        const float* Ws[11] = {W_sa_qkv, CW0, CW1, W_ca_q, CW2, CW3,
                               W_ca_kv, CW4, CW5, W_proj_sa, W_proj_ca};
        ushort* Ds[11] = {WsaqH, C0H, C1H, WcqH, C2H, C3H,
                          WckH, C4H, C5H, WpsH, WpcH};
        int NCs[11] = {576,576,576,192,192,192,384,384,384,192,192};
        int bs[12] = {0,432,864,1296,1440,1584,1728,2016,2304,2592,2736,2880};
        for (int i = 0; i < 11; ++i) { J.W[i]=Ws[i]; J.dh[i]=Ds[i]; J.NC[i]=NCs[i]; }
        for (int i = 0; i < 12; ++i) J.base[i] = bs[i];
        conv_wT_all<<<2880, 256, 0, stream>>>(J);
    }

    // ---- chunking: 188160 bytes per batch element, 64KB tail pad ----
    long long avail = (long long)ws_size - 442368LL * 4 - 737280LL * 2 - 65536;
    int cbmax = (int)(avail / 188160);
    if (cbmax > 2048) cbmax = 2048;
    if (cbmax < 1) cbmax = 1;

    const long long OUT1 = 2LL * 2048 * 49 * 192;
    dim3 blk(256);

    for (int c0 = 0; c0 < 2048; c0 += cbmax) {
        int cb = (c0 + cbmax <= 2048) ? cbmax : (2048 - c0);
        int M = cb * 49;
        long long SS = (long long)M * 32;
        int gy = (M + 63) / 64;
        int cblk = (int)(((long long)M * 48 + 255) / 256);
        if (cblk > 4096) cblk = 4096;

        dim3 g1(3, gy, 2), g2(1, gy, 2), g3(2, gy, 2);

        // =========================== SA branch ===========================
        ushort* XtH = chunkU;                              // [6][M][32]
        ushort* XrH = XtH + (long long)cbmax * 9408;
        ushort* QtH = XrH + (long long)cbmax * 9408;       // [18][M][32]
        ushort* QrH = QtH + (long long)cbmax * 28224;
        ushort* OtH = QrH + (long long)cbmax * 28224;      // [6][M][32]
        ushort* OrH = OtH + (long long)cbmax * 9408;

        conv_x2<<<cblk, blk, 0, stream>>>(
            x_sa + (long long)c0 * 9408, x_sa + (2048LL + c0) * 9408, 9408,
            XtH, XrH, M);

        gemm_f16<576, true, false><<<g1, blk, 0, stream>>>(
            XtH, XrH, C0H, QtH, nullptr,
            XrH, XtH, C1H, QrH, nullptr,
            WsaqH, b_sa_qkv, 0, M);

        attn_f16<<<cb * 6, blk, 0, stream>>>(
            QtH, QtH + 6 * SS, QtH + 12 * SS,
            QrH, QrH + 6 * SS, QrH + 12 * SS,
            SS, rpb, lam_sa, OtH, OrH);

        gemm_f16<192, false, true><<<g2, blk, 0, stream>>>(
            OtH, nullptr, nullptr, nullptr, out + (long long)c0 * 9408,
            OrH, nullptr, nullptr, nullptr, out + (2048LL + c0) * 9408,
            WpsH, b_proj_sa, 9408, M);

        // =========================== CA branch ===========================
        ushort* CXtH = chunkU;                             // [6][M][32]
        ushort* CXrH = CXtH + (long long)cbmax * 9408;
        ushort* CQtH = CXrH + (long long)cbmax * 9408;     // [6][M][32]
        ushort* CQrH = CQtH + (long long)cbmax * 9408;
        ushort* KtH  = CQrH + (long long)cbmax * 9408;     // [12][M][32]
        ushort* KrH  = KtH + (long long)cbmax * 18816;
        ushort* COtH = KrH + (long long)cbmax * 18816;     // [6][M][32]
        ushort* COrH = COtH + (long long)cbmax * 9408;

        conv_x2<<<cblk, blk, 0, stream>>>(
            x_ca + (long long)c0 * 18816, x_ca + (long long)c0 * 18816 + 9408, 18816,
            CXtH, CXrH, M);

        gemm_f16<192, true, false><<<g2, blk, 0, stream>>>(
            CXtH, CXrH, C2H, CQtH, nullptr,
            CXrH, CXtH, C3H, CQrH, nullptr,
            WcqH, b_ca_q, 0, M);

        gemm_f16<384, true, false><<<g3, blk, 0, stream>>>(
            CXtH, CXrH, C4H, KtH, nullptr,
            CXrH, CXtH, C5H, KrH, nullptr,
            WckH, b_ca_kv, 0, M);

        attn_f16<<<cb * 6, blk, 0, stream>>>(
            CQtH, KtH, KtH + 6 * SS,
            CQrH, KrH, KrH + 6 * SS,
            SS, rpb, lam_ca, COtH, COrH);

        gemm_f16<192, false, true><<<g2, blk, 0, stream>>>(
            COtH, nullptr, nullptr, nullptr, out + OUT1 + (long long)c0 * 18816,
            COrH, nullptr, nullptr, nullptr, out + OUT1 + (long long)c0 * 18816 + 9408,
            WpcH, b_proj_ca, 18816, M);
    }
}